// Round 13
// baseline (284.392 us; speedup 1.0000x reference)
//
#include <hip/hip_runtime.h>
#include <math.h>

#define HH 224
#define WW 224
#define TH 32
#define TW 32
#define TILES_X 7
#define HALO 36
#define BOXH 56
#define BOXW 57          // LDS stride for the source box (+1 high-end pad)
#define WTS  40          // 160B rows -> float4-aligned
#define TMPS 40

typedef float nt_float4 __attribute__((ext_vector_type(4)));  // native vec for nontemporal builtins

struct __align__(16) ImgParams {
    float ca, sa, ay, by;   // rotation + y-affine (sy = ay*yr + by)
    float ax, bx, w0, w1;   // x-affine (flip folded in) + blur taps
    float w2, w3, w4, pad;
};

// ---------------- copy_list: compacted non-augmented channels ----------------
__global__ void copylist_kernel(const int* __restrict__ channel_idx, int n_aug, int c,
                                int* __restrict__ copy_list, int* __restrict__ mark) {
    int t = threadIdx.x;
    for (int i = t; i < c; i += 256) mark[i] = 0;
    __syncthreads();
    for (int i = t; i < n_aug; i += 256) mark[channel_idx[i]] = 1;
    __syncthreads();
    __shared__ int cnt;
    if (t == 0) cnt = 0;
    __syncthreads();
    for (int i = t; i < c; i += 256) {
        if (!mark[i]) {
            int p = atomicAdd(&cnt, 1);
            copy_list[p] = i;
        }
    }
}

// ---------------- per-image params: all transcendentals, once per image ----------------
__global__ void params_kernel(const float* __restrict__ aug_u,
                              ImgParams* __restrict__ params, int N) {
    int n = blockIdx.x * blockDim.x + threadIdx.x;
    if (n >= N) return;
    const float* u = aug_u + (size_t)n * 7;
    const float u0 = u[0], u1 = u[1], u2 = u[2], u3 = u[3], u4 = u[4], u5 = u[5], u6 = u[6];

    const float area  = (float)(HH * WW) * (0.8f + 0.2f * u0);
    const float lo    = logf(0.75f);
    const float hi    = logf(4.0f / 3.0f);
    const float ratio = expf(lo + (hi - lo) * u1);
    float wc = sqrtf(area * ratio);
    float hc = sqrtf(area / ratio);
    wc = fminf(fmaxf(wc, 1.0f), (float)WW);
    hc = fminf(fmaxf(hc, 1.0f), (float)HH);
    const float fi    = u2 * ((float)HH - hc);
    const float fj    = u3 * ((float)WW - wc);
    const bool  flip  = u4 < 0.5f;
    const float angle = u5 * 3.14159274101257324f;
    const float sigma = 0.1f + 1.9f * u6;

    ImgParams p;
    p.ca = cosf(angle);
    p.sa = sinf(angle);
    const float syk = hc / (float)HH;
    const float sxk = wc / (float)WW;
    p.ay = syk;
    p.by = 0.5f * syk - 0.5f + fi;
    if (flip) {
        p.ax = -sxk;
        p.bx = ((float)WW - 0.5f) * sxk - 0.5f + fj;
    } else {
        p.ax = sxk;
        p.bx = 0.5f * sxk - 0.5f + fj;
    }
    float wk[5], wsum = 0.f;
    const float inv2s2 = 1.0f / (2.0f * sigma * sigma);
    #pragma unroll
    for (int k = 0; k < 5; ++k) {
        float d = (float)k - 2.0f;
        wk[k] = expf(-(d * d) * inv2s2);
        wsum += wk[k];
    }
    float inv = 1.0f / wsum;
    p.w0 = wk[0] * inv; p.w1 = wk[1] * inv; p.w2 = wk[2] * inv;
    p.w3 = wk[3] * inv; p.w4 = wk[4] * inv;
    p.pad = 0.f;
    params[n] = p;
}

__device__ __forceinline__ void swz_decode(int id, int swz, int& unit, int& tile) {
    if (swz) {
        int low  = id & 7;
        int rest = id >> 3;
        int uh   = rest / 49;
        tile     = rest - uh * 49;
        unit     = (uh << 3) | low;
    } else {
        unit = id / 49;
        tile = id - unit * 49;
    }
}

// ---------------- fused: interleaved augment/copy blocks ----------------
// mode 2: chunks of 8 alternate aug/copy (balanced + XCD-aligned); 1: serial sections + swz; 0: serial, no swz
__global__ __launch_bounds__(256) void fused_kernel(
        const float* __restrict__ M, const int* __restrict__ channel_idx,
        const int* __restrict__ copy_list, const ImgParams* __restrict__ params,
        const float* __restrict__ noise, float* __restrict__ out,
        int c, int n_aug, int n_copy, int aug_blocks, int mode) {
    const int tid = threadIdx.x;
    const int id  = blockIdx.x;

    int type, local;
    if (mode == 2) {
        int chunk = id >> 3, lane = id & 7;
        type  = chunk & 1;
        local = (((chunk >> 1) << 3) | lane);
    } else {
        type  = (id >= aug_blocks) ? 1 : 0;
        local = type ? id - aug_blocks : id;
    }
    int unit, tile;
    swz_decode(local, mode >= 1, unit, tile);

    if (type) {
        // -------- copy path: balanced across XCDs by construction --------
        const int bi = unit / n_copy;
        const int ci = unit - bi * n_copy;
        const int ch = copy_list[ci];
        const size_t chanoff = ((size_t)bi * c + ch) * (HH * WW);
        const nt_float4* __restrict__ src = (const nt_float4*)(M + chanoff);
        nt_float4* __restrict__ dst = (nt_float4*)(out + chanoff);
        int off = tile * 256 + tid;
        __builtin_nontemporal_store(__builtin_nontemporal_load(&src[off]), &dst[off]);
        return;
    }

    // -------- augment path --------
    const int bi = unit / n_aug;
    const int a  = unit - bi * n_aug;
    const int ch = channel_idx[a];
    const int n  = unit;                    // bi * n_aug + a
    const size_t chanoff = ((size_t)bi * c + ch) * (HH * WW);

    const int ty = tile / TILES_X;
    const int y0 = ty * TH;
    const int x0 = (tile - ty * TILES_X) * TW;

    const ImgParams P = params[n];          // uniform -> scalar loads
    const float* __restrict__ img = M + chanoff;

    __shared__ __align__(16) float Box[BOXH * BOXW];   // 12.8 KB; aliased as Tmp later
    __shared__ __align__(16) float Wt[HALO][WTS];      // 5.8 KB

    const float cc = 111.5f;

    // ---- bounding box of source coords (block-uniform scalar math) ----
    const int ry_lo = max(y0 - 2, 0),  ry_hi = min(y0 + 33, HH - 1);
    const int rx_lo = max(x0 - 2, 0),  rx_hi = min(x0 + 33, WW - 1);
    const float dyl = (float)ry_lo - cc, dyh = (float)ry_hi - cc;
    const float dxl = (float)rx_lo - cc, dxh = (float)rx_hi - cc;
    float yr_min = cc + fminf(P.ca * dyl, P.ca * dyh) + P.sa * dxl;
    float yr_max = cc + fmaxf(P.ca * dyl, P.ca * dyh) + P.sa * dxh;
    float xr_min = cc + fminf(P.ca * dxl, P.ca * dxh) - P.sa * dyh;
    float xr_max = cc + fmaxf(P.ca * dxl, P.ca * dxh) - P.sa * dyl;
    yr_min = fmaxf(yr_min, -0.5f); yr_max = fminf(yr_max, (float)HH - 0.5f);
    xr_min = fmaxf(xr_min, -0.5f); xr_max = fminf(xr_max, (float)WW - 0.5f);
    const float sy_min = P.ay * yr_min + P.by, sy_max = P.ay * yr_max + P.by;
    const float sx_a = P.ax * xr_min + P.bx,  sx_b = P.ax * xr_max + P.bx;
    const float sx_min = fminf(sx_a, sx_b), sx_max = fmaxf(sx_a, sx_b);
    const int by0 = min(max((int)floorf(sy_min), 0), HH - 1);
    const int by1 = min(max((int)floorf(sy_max) + 1, 0), HH - 1);
    const int bx0 = min(max((int)floorf(sx_min), 0), WW - 1);
    const int bx1 = min(max((int)floorf(sx_max) + 1, 0), WW - 1);
    const int bh = max(by1 - by0 + 1, 0);   // <= 52 rows of real data
    const int bw = bx1 - bx0 + 1;           // <= 52 cols

    // ---- coalesced load of the box into LDS, +1 high-end pad (clamped src) ----
    // Reference clamps yi FIRST, then neighbor is yi+1 (re-clamped): per-sample
    // clamp on the low side stays; pad only absorbs the +1 neighbor at 223.
    {
        const int q = tid & 63;
        if (q <= bw) {
            int scol = min(bx0 + q, WW - 1);
            for (int r = tid >> 6; r <= bh; r += 4) {
                int srow = min(by0 + r, WW - 1);
                Box[r * BOXW + q] = img[srow * WW + scol];
            }
        }
    }

    // ---- hoist noise load: issue now, consume after the last barrier ----
    const float* __restrict__ npz = noise + (size_t)n * (HH * WW);
    const size_t o_out = (size_t)(y0 + (tid >> 3)) * WW + (x0 + 4 * (tid & 7));
    nt_float4 nz = __builtin_nontemporal_load((const nt_float4*)(npz + o_out));

    __syncthreads();

    // ---- warp into halo tile: thread = (row, 6 consecutive x) ----
    // NOTE: per-sample math uses the EXACT reference association
    // (yr = ca*dy + sa*dx + cc, explicit range check) — feeding the
    // discontinuous inb/zero-fill decision; do NOT re-associate (round-6 fail).
    if (tid < 216) {
        const int hy  = tid / 6;
        const int g   = tid - hy * 6;
        const int hx0 = g * 6;
        int vy = y0 + hy - 2;
        int ayv = abs(vy);
        int ry = min(ayv, 2 * (HH - 1) - ayv);   // reflect
        const float dy = (float)ry - cc;
        const int kbase = -(by0 * BOXW + bx0);
        float acc[6];
        #pragma unroll
        for (int j = 0; j < 6; ++j) {
            int vx = x0 + hx0 + j - 2;
            int axv = abs(vx);
            int rx = min(axv, 2 * (WW - 1) - axv);
            float dx = (float)rx - cc;
            float yr = P.ca * dy + P.sa * dx + cc;
            float xr = P.ca * dx - P.sa * dy + cc;
            float val = 0.f;
            if (yr >= -0.5f && yr <= (float)HH - 0.5f &&
                xr >= -0.5f && xr <= (float)WW - 0.5f) {
                float sy = P.ay * yr + P.by;
                float sx = P.ax * xr + P.bx;
                float fy = floorf(sy), fx = floorf(sx);
                float wy = sy - fy, wx = sx - fx;
                int yi = min(max((int)fy, 0), HH - 1);   // clamp FIRST (ref order)
                int xi = min(max((int)fx, 0), WW - 1);
                int k = yi * BOXW + xi + kbase;
                float v00 = Box[k],        v01 = Box[k + 1];
                float v10 = Box[k + BOXW], v11 = Box[k + BOXW + 1];
                float top = v00 + (v01 - v00) * wx;
                float bot = v10 + (v11 - v10) * wx;
                val = top + (bot - top) * wy;
            }
            acc[j] = val;
        }
        float2* wrow = (float2*)&Wt[hy][hx0];
        wrow[0] = make_float2(acc[0], acc[1]);
        wrow[1] = make_float2(acc[2], acc[3]);
        wrow[2] = make_float2(acc[4], acc[5]);
    }
    __syncthreads();

    // ---- vertical blur: 32 rows x 9 col-quads, float4 ----
    float* __restrict__ Tmp = Box;   // alias; safe after barrier
    for (int u2 = tid; u2 < TH * 9; u2 += 256) {
        int vy = u2 / 9, q = u2 - vy * 9;
        int x = 4 * q;
        float4 a0 = *(const float4*)&Wt[vy][x];
        float4 a1 = *(const float4*)&Wt[vy + 1][x];
        float4 a2 = *(const float4*)&Wt[vy + 2][x];
        float4 a3 = *(const float4*)&Wt[vy + 3][x];
        float4 a4 = *(const float4*)&Wt[vy + 4][x];
        float4 s;
        s.x = P.w0 * a0.x + P.w1 * a1.x + P.w2 * a2.x + P.w3 * a3.x + P.w4 * a4.x;
        s.y = P.w0 * a0.y + P.w1 * a1.y + P.w2 * a2.y + P.w3 * a3.y + P.w4 * a4.y;
        s.z = P.w0 * a0.z + P.w1 * a1.z + P.w2 * a2.z + P.w3 * a3.z + P.w4 * a4.z;
        s.w = P.w0 * a0.w + P.w1 * a1.w + P.w2 * a2.w + P.w3 * a3.w + P.w4 * a4.w;
        *(float4*)&Tmp[vy * TMPS + x] = s;
    }
    __syncthreads();

    // ---- horizontal blur + noise + write, 4 px/thread, float4 ----
    float* __restrict__ op = out + chanoff;
    {
        int yy = tid >> 3, p = tid & 7;
        int x = 4 * p;
        const float* t = Tmp + yy * TMPS + x;
        float4 ta = *(const float4*)(t);       // t0..t3
        float4 tb = *(const float4*)(t + 4);   // t4..t7
        float s0 = P.w0 * ta.x + P.w1 * ta.y + P.w2 * ta.z + P.w3 * ta.w + P.w4 * tb.x;
        float s1 = P.w0 * ta.y + P.w1 * ta.z + P.w2 * ta.w + P.w3 * tb.x + P.w4 * tb.y;
        float s2 = P.w0 * ta.z + P.w1 * ta.w + P.w2 * tb.x + P.w3 * tb.y + P.w4 * tb.z;
        float s3 = P.w0 * ta.w + P.w1 * tb.x + P.w2 * tb.y + P.w3 * tb.z + P.w4 * tb.w;
        nt_float4 r;
        r.x = s0 + 0.05f * nz.x; r.y = s1 + 0.05f * nz.y;
        r.z = s2 + 0.05f * nz.z; r.w = s3 + 0.05f * nz.w;
        __builtin_nontemporal_store(r, (nt_float4*)(op + o_out));
    }
}

extern "C" void kernel_launch(void* const* d_in, const int* in_sizes, int n_in,
                              void* d_out, int out_size, void* d_ws, size_t ws_size,
                              hipStream_t stream) {
    const float* M           = (const float*)d_in[0];
    const int*   channel_idx = (const int*)d_in[1];
    const float* aug_u       = (const float*)d_in[2];
    const float* noise       = (const float*)d_in[3];
    float* out = (float*)d_out;

    const int n_aug = in_sizes[1];
    const int b     = in_sizes[2] / (n_aug * 7);
    const int c     = in_sizes[0] / (b * HH * WW);
    const int N     = b * n_aug;
    const int n_copy = c - n_aug;

    int* copy_list = (int*)d_ws;
    int* mark      = (int*)((char*)d_ws + 2048);
    ImgParams* params = (ImgParams*)((char*)d_ws + 8192);

    copylist_kernel<<<1, 256, 0, stream>>>(channel_idx, n_aug, c, copy_list, mark);
    params_kernel<<<(N + 255) / 256, 256, 0, stream>>>(aug_u, params, N);

    const int aug_units  = b * n_aug;
    const int copy_units = b * n_copy;
    const int aug_blocks = 49 * aug_units;
    const int copy_blocks = 49 * copy_units;

    int mode;
    if (aug_blocks == copy_blocks && aug_units % 8 == 0) {
        mode = 2;                                   // fine-grained interleave + swizzle
    } else if (aug_units % 8 == 0 && copy_units % 8 == 0) {
        mode = 1;                                   // serial sections + swizzle
    } else {
        mode = 0;                                   // serial sections, no swizzle
    }
    fused_kernel<<<aug_blocks + copy_blocks, 256, 0, stream>>>(
        M, channel_idx, copy_list, params, noise, out,
        c, n_aug, n_copy, aug_blocks, mode);
}

// Round 14
// 233.401 us; speedup vs baseline: 1.2185x; 1.2185x over previous
//
#include <hip/hip_runtime.h>
#include <math.h>

#define HH 224
#define WW 224
#define TH 32
#define TW 32
#define TILES_X 7
#define HALO 36
#define BOXH 56
#define BOXW 57          // LDS stride for the source box (+1 high-end pad)
#define WTS  40          // 160B rows -> float4-aligned
#define TMPS 40
#define NFAT 512         // fat copy blocks (2 per CU), dispatched first

typedef float nt_float4 __attribute__((ext_vector_type(4)));  // native vec for nontemporal builtins

struct __align__(16) ImgParams {
    float ca, sa, ay, by;   // rotation + y-affine (sy = ay*yr + by)
    float ax, bx, w0, w1;   // x-affine (flip folded in) + blur taps
    float w2, w3, w4, pad;
};

// ---------------- copy_list: compacted non-augmented channels ----------------
__global__ void copylist_kernel(const int* __restrict__ channel_idx, int n_aug, int c,
                                int* __restrict__ copy_list, int* __restrict__ mark) {
    int t = threadIdx.x;
    for (int i = t; i < c; i += 256) mark[i] = 0;
    __syncthreads();
    for (int i = t; i < n_aug; i += 256) mark[channel_idx[i]] = 1;
    __syncthreads();
    __shared__ int cnt;
    if (t == 0) cnt = 0;
    __syncthreads();
    for (int i = t; i < c; i += 256) {
        if (!mark[i]) {
            int p = atomicAdd(&cnt, 1);
            copy_list[p] = i;
        }
    }
}

// ---------------- per-image params: all transcendentals, once per image ----------------
__global__ void params_kernel(const float* __restrict__ aug_u,
                              ImgParams* __restrict__ params, int N) {
    int n = blockIdx.x * blockDim.x + threadIdx.x;
    if (n >= N) return;
    const float* u = aug_u + (size_t)n * 7;
    const float u0 = u[0], u1 = u[1], u2 = u[2], u3 = u[3], u4 = u[4], u5 = u[5], u6 = u[6];

    const float area  = (float)(HH * WW) * (0.8f + 0.2f * u0);
    const float lo    = logf(0.75f);
    const float hi    = logf(4.0f / 3.0f);
    const float ratio = expf(lo + (hi - lo) * u1);
    float wc = sqrtf(area * ratio);
    float hc = sqrtf(area / ratio);
    wc = fminf(fmaxf(wc, 1.0f), (float)WW);
    hc = fminf(fmaxf(hc, 1.0f), (float)HH);
    const float fi    = u2 * ((float)HH - hc);
    const float fj    = u3 * ((float)WW - wc);
    const bool  flip  = u4 < 0.5f;
    const float angle = u5 * 3.14159274101257324f;
    const float sigma = 0.1f + 1.9f * u6;

    ImgParams p;
    p.ca = cosf(angle);
    p.sa = sinf(angle);
    const float syk = hc / (float)HH;
    const float sxk = wc / (float)WW;
    p.ay = syk;
    p.by = 0.5f * syk - 0.5f + fi;
    if (flip) {
        p.ax = -sxk;
        p.bx = ((float)WW - 0.5f) * sxk - 0.5f + fj;
    } else {
        p.ax = sxk;
        p.bx = 0.5f * sxk - 0.5f + fj;
    }
    float wk[5], wsum = 0.f;
    const float inv2s2 = 1.0f / (2.0f * sigma * sigma);
    #pragma unroll
    for (int k = 0; k < 5; ++k) {
        float d = (float)k - 2.0f;
        wk[k] = expf(-(d * d) * inv2s2);
        wsum += wk[k];
    }
    float inv = 1.0f / wsum;
    p.w0 = wk[0] * inv; p.w1 = wk[1] * inv; p.w2 = wk[2] * inv;
    p.w3 = wk[3] * inv; p.w4 = wk[4] * inv;
    p.pad = 0.f;
    params[n] = p;
}

__device__ __forceinline__ void swz_decode(int id, int swz, int& unit, int& tile) {
    if (swz) {
        int low  = id & 7;
        int rest = id >> 3;
        int uh   = rest / 49;
        tile     = rest - uh * 49;
        unit     = (uh << 3) | low;
    } else {
        unit = id / 49;
        tile = id - unit * 49;
    }
}

// ---------------- fused: fat copy blocks first, then augment blocks ----------------
__global__ __launch_bounds__(256) void fused_kernel(
        const float* __restrict__ M, const int* __restrict__ channel_idx,
        const int* __restrict__ copy_list, const ImgParams* __restrict__ params,
        const float* __restrict__ noise, float* __restrict__ out,
        int c, int n_aug, int n_copy, int copy_units, int nfat, int swz) {
    const int tid = threadIdx.x;
    const int id  = blockIdx.x;

    if (id < nfat) {
        // -------- fat copy blocks: long-lived, 2/CU, stream under the aug work --------
        if (swz) {
            // XCD-pinned: this block only copies units with unit%8 == id%8
            const int r = id & 7, s = id >> 3;          // s in [0, nfat/8)
            const int per = copy_units >> 3;            // units per residue
            for (int m = s; m < per; m += (nfat >> 3)) {
                const int unit = (m << 3) | r;
                const int bi = unit / n_copy;
                const int ci = unit - bi * n_copy;
                const size_t chanoff = ((size_t)bi * c + copy_list[ci]) * (HH * WW);
                const nt_float4* __restrict__ src = (const nt_float4*)(M + chanoff);
                nt_float4* __restrict__ dst = (nt_float4*)(out + chanoff);
                #pragma unroll 4
                for (int off = tid; off < 49 * 256; off += 256)
                    __builtin_nontemporal_store(__builtin_nontemporal_load(&src[off]), &dst[off]);
            }
        } else {
            const int total = copy_units * 49;
            for (int item = id; item < total; item += nfat) {
                const int unit = item / 49;
                const int t2   = item - unit * 49;
                const int bi = unit / n_copy;
                const int ci = unit - bi * n_copy;
                const size_t chanoff = ((size_t)bi * c + copy_list[ci]) * (HH * WW);
                const nt_float4* __restrict__ src = (const nt_float4*)(M + chanoff);
                nt_float4* __restrict__ dst = (nt_float4*)(out + chanoff);
                int off = t2 * 256 + tid;
                __builtin_nontemporal_store(__builtin_nontemporal_load(&src[off]), &dst[off]);
            }
        }
        return;
    }

    // -------- augment path (r12 structure, unchanged) --------
    int unit, tile;
    swz_decode(id - nfat, swz, unit, tile);
    const int bi = unit / n_aug;
    const int a  = unit - bi * n_aug;
    const int ch = channel_idx[a];
    const int n  = unit;                    // bi * n_aug + a
    const size_t chanoff = ((size_t)bi * c + ch) * (HH * WW);

    const int ty = tile / TILES_X;
    const int y0 = ty * TH;
    const int x0 = (tile - ty * TILES_X) * TW;

    const ImgParams P = params[n];          // uniform -> scalar loads
    const float* __restrict__ img = M + chanoff;

    __shared__ __align__(16) float Box[BOXH * BOXW];   // 12.8 KB; aliased as Tmp later
    __shared__ __align__(16) float Wt[HALO][WTS];      // 5.8 KB

    const float cc = 111.5f;

    // ---- bounding box of source coords (block-uniform scalar math) ----
    const int ry_lo = max(y0 - 2, 0),  ry_hi = min(y0 + 33, HH - 1);
    const int rx_lo = max(x0 - 2, 0),  rx_hi = min(x0 + 33, WW - 1);
    const float dyl = (float)ry_lo - cc, dyh = (float)ry_hi - cc;
    const float dxl = (float)rx_lo - cc, dxh = (float)rx_hi - cc;
    float yr_min = cc + fminf(P.ca * dyl, P.ca * dyh) + P.sa * dxl;
    float yr_max = cc + fmaxf(P.ca * dyl, P.ca * dyh) + P.sa * dxh;
    float xr_min = cc + fminf(P.ca * dxl, P.ca * dxh) - P.sa * dyh;
    float xr_max = cc + fmaxf(P.ca * dxl, P.ca * dxh) - P.sa * dyl;
    yr_min = fmaxf(yr_min, -0.5f); yr_max = fminf(yr_max, (float)HH - 0.5f);
    xr_min = fmaxf(xr_min, -0.5f); xr_max = fminf(xr_max, (float)WW - 0.5f);
    const float sy_min = P.ay * yr_min + P.by, sy_max = P.ay * yr_max + P.by;
    const float sx_a = P.ax * xr_min + P.bx,  sx_b = P.ax * xr_max + P.bx;
    const float sx_min = fminf(sx_a, sx_b), sx_max = fmaxf(sx_a, sx_b);
    const int by0 = min(max((int)floorf(sy_min), 0), HH - 1);
    const int by1 = min(max((int)floorf(sy_max) + 1, 0), HH - 1);
    const int bx0 = min(max((int)floorf(sx_min), 0), WW - 1);
    const int bx1 = min(max((int)floorf(sx_max) + 1, 0), WW - 1);
    const int bh = max(by1 - by0 + 1, 0);   // <= 52 rows of real data
    const int bw = bx1 - bx0 + 1;           // <= 52 cols

    // ---- coalesced load of the box into LDS, +1 high-end pad (clamped src) ----
    // Reference clamps yi FIRST, then neighbor is yi+1 (re-clamped): per-sample
    // clamp on the low side stays; pad only absorbs the +1 neighbor at 223.
    {
        const int q = tid & 63;
        if (q <= bw) {
            int scol = min(bx0 + q, WW - 1);
            for (int r = tid >> 6; r <= bh; r += 4) {
                int srow = min(by0 + r, HH - 1);
                Box[r * BOXW + q] = img[srow * WW + scol];
            }
        }
    }
    __syncthreads();

    // ---- warp into halo tile: thread = (row, 6 consecutive x) ----
    // NOTE: per-sample math uses the EXACT reference association
    // (yr = ca*dy + sa*dx + cc, explicit range check) — feeding the
    // discontinuous inb/zero-fill decision; do NOT re-associate (round-6 fail).
    if (tid < 216) {
        const int hy  = tid / 6;
        const int g   = tid - hy * 6;
        const int hx0 = g * 6;
        int vy = y0 + hy - 2;
        int ayv = abs(vy);
        int ry = min(ayv, 2 * (HH - 1) - ayv);   // reflect
        const float dy = (float)ry - cc;
        const int kbase = -(by0 * BOXW + bx0);
        float acc[6];
        #pragma unroll
        for (int j = 0; j < 6; ++j) {
            int vx = x0 + hx0 + j - 2;
            int axv = abs(vx);
            int rx = min(axv, 2 * (WW - 1) - axv);
            float dx = (float)rx - cc;
            float yr = P.ca * dy + P.sa * dx + cc;
            float xr = P.ca * dx - P.sa * dy + cc;
            float val = 0.f;
            if (yr >= -0.5f && yr <= (float)HH - 0.5f &&
                xr >= -0.5f && xr <= (float)WW - 0.5f) {
                float sy = P.ay * yr + P.by;
                float sx = P.ax * xr + P.bx;
                float fy = floorf(sy), fx = floorf(sx);
                float wy = sy - fy, wx = sx - fx;
                int yi = min(max((int)fy, 0), HH - 1);   // clamp FIRST (ref order)
                int xi = min(max((int)fx, 0), WW - 1);
                int k = yi * BOXW + xi + kbase;
                float v00 = Box[k],        v01 = Box[k + 1];
                float v10 = Box[k + BOXW], v11 = Box[k + BOXW + 1];
                float top = v00 + (v01 - v00) * wx;
                float bot = v10 + (v11 - v10) * wx;
                val = top + (bot - top) * wy;
            }
            acc[j] = val;
        }
        float2* wrow = (float2*)&Wt[hy][hx0];
        wrow[0] = make_float2(acc[0], acc[1]);
        wrow[1] = make_float2(acc[2], acc[3]);
        wrow[2] = make_float2(acc[4], acc[5]);
    }
    __syncthreads();

    // ---- vertical blur: 32 rows x 9 col-quads, float4 ----
    float* __restrict__ Tmp = Box;   // alias; safe after barrier
    for (int u2 = tid; u2 < TH * 9; u2 += 256) {
        int vy = u2 / 9, q = u2 - vy * 9;
        int x = 4 * q;
        float4 a0 = *(const float4*)&Wt[vy][x];
        float4 a1 = *(const float4*)&Wt[vy + 1][x];
        float4 a2 = *(const float4*)&Wt[vy + 2][x];
        float4 a3 = *(const float4*)&Wt[vy + 3][x];
        float4 a4 = *(const float4*)&Wt[vy + 4][x];
        float4 s;
        s.x = P.w0 * a0.x + P.w1 * a1.x + P.w2 * a2.x + P.w3 * a3.x + P.w4 * a4.x;
        s.y = P.w0 * a0.y + P.w1 * a1.y + P.w2 * a2.y + P.w3 * a3.y + P.w4 * a4.y;
        s.z = P.w0 * a0.z + P.w1 * a1.z + P.w2 * a2.z + P.w3 * a3.z + P.w4 * a4.z;
        s.w = P.w0 * a0.w + P.w1 * a1.w + P.w2 * a2.w + P.w3 * a3.w + P.w4 * a4.w;
        *(float4*)&Tmp[vy * TMPS + x] = s;
    }
    __syncthreads();

    // ---- horizontal blur + noise + write, 4 px/thread, float4 ----
    const float* __restrict__ npz = noise + (size_t)n * (HH * WW);
    float* __restrict__ op = out + chanoff;
    {
        int yy = tid >> 3, p = tid & 7;
        int x = 4 * p;
        const float* t = Tmp + yy * TMPS + x;
        float4 ta = *(const float4*)(t);       // t0..t3
        float4 tb = *(const float4*)(t + 4);   // t4..t7
        float s0 = P.w0 * ta.x + P.w1 * ta.y + P.w2 * ta.z + P.w3 * ta.w + P.w4 * tb.x;
        float s1 = P.w0 * ta.y + P.w1 * ta.z + P.w2 * ta.w + P.w3 * tb.x + P.w4 * tb.y;
        float s2 = P.w0 * ta.z + P.w1 * ta.w + P.w2 * tb.x + P.w3 * tb.y + P.w4 * tb.z;
        float s3 = P.w0 * ta.w + P.w1 * tb.x + P.w2 * tb.y + P.w3 * tb.z + P.w4 * tb.w;
        size_t o = (size_t)(y0 + yy) * WW + (x0 + x);
        nt_float4 nz = __builtin_nontemporal_load((const nt_float4*)(npz + o));
        nt_float4 r;
        r.x = s0 + 0.05f * nz.x; r.y = s1 + 0.05f * nz.y;
        r.z = s2 + 0.05f * nz.z; r.w = s3 + 0.05f * nz.w;
        __builtin_nontemporal_store(r, (nt_float4*)(op + o));
    }
}

extern "C" void kernel_launch(void* const* d_in, const int* in_sizes, int n_in,
                              void* d_out, int out_size, void* d_ws, size_t ws_size,
                              hipStream_t stream) {
    const float* M           = (const float*)d_in[0];
    const int*   channel_idx = (const int*)d_in[1];
    const float* aug_u       = (const float*)d_in[2];
    const float* noise       = (const float*)d_in[3];
    float* out = (float*)d_out;

    const int n_aug = in_sizes[1];
    const int b     = in_sizes[2] / (n_aug * 7);
    const int c     = in_sizes[0] / (b * HH * WW);
    const int N     = b * n_aug;
    const int n_copy = c - n_aug;

    int* copy_list = (int*)d_ws;
    int* mark      = (int*)((char*)d_ws + 2048);
    ImgParams* params = (ImgParams*)((char*)d_ws + 8192);

    copylist_kernel<<<1, 256, 0, stream>>>(channel_idx, n_aug, c, copy_list, mark);
    params_kernel<<<(N + 255) / 256, 256, 0, stream>>>(aug_u, params, N);

    const int aug_units  = b * n_aug;
    const int copy_units = b * n_copy;
    const int aug_blocks = 49 * aug_units;
    // swizzle requires residue-aligned sections
    const int swz  = (aug_units % 8 == 0 && copy_units % 8 == 0) ? 1 : 0;
    const int nfat = (copy_units > 0) ? min(NFAT, copy_units * 49) : 0;
    fused_kernel<<<nfat + aug_blocks, 256, 0, stream>>>(
        M, channel_idx, copy_list, params, noise, out,
        c, n_aug, n_copy, copy_units, nfat, swz);
}

// Round 15
// 225.976 us; speedup vs baseline: 1.2585x; 1.0329x over previous
//
#include <hip/hip_runtime.h>
#include <math.h>

#define HH 224
#define WW 224
#define TH 32
#define TW 32
#define TILES_X 7
#define HALO 36
#define BOXH 56
#define BOXW 57          // LDS stride for the source box (+1 high-end pad)
#define WTS  40          // 160B rows -> float4-aligned
#define TMPS 40

typedef float nt_float4 __attribute__((ext_vector_type(4)));  // native vec for nontemporal builtins

struct __align__(16) ImgParams {
    float ca, sa, ay, by;   // rotation + y-affine (sy = ay*yr + by)
    float ax, bx, w0, w1;   // x-affine (flip folded in) + blur taps
    float w2, w3, w4, pad;
};

// ---------------- copy_list: compacted non-augmented channels ----------------
__global__ void copylist_kernel(const int* __restrict__ channel_idx, int n_aug, int c,
                                int* __restrict__ copy_list, int* __restrict__ mark) {
    int t = threadIdx.x;
    for (int i = t; i < c; i += 256) mark[i] = 0;
    __syncthreads();
    for (int i = t; i < n_aug; i += 256) mark[channel_idx[i]] = 1;
    __syncthreads();
    __shared__ int cnt;
    if (t == 0) cnt = 0;
    __syncthreads();
    for (int i = t; i < c; i += 256) {
        if (!mark[i]) {
            int p = atomicAdd(&cnt, 1);
            copy_list[p] = i;
        }
    }
}

// ---------------- per-image params: all transcendentals, once per image ----------------
__global__ void params_kernel(const float* __restrict__ aug_u,
                              ImgParams* __restrict__ params, int N) {
    int n = blockIdx.x * blockDim.x + threadIdx.x;
    if (n >= N) return;
    const float* u = aug_u + (size_t)n * 7;
    const float u0 = u[0], u1 = u[1], u2 = u[2], u3 = u[3], u4 = u[4], u5 = u[5], u6 = u[6];

    const float area  = (float)(HH * WW) * (0.8f + 0.2f * u0);
    const float lo    = logf(0.75f);
    const float hi    = logf(4.0f / 3.0f);
    const float ratio = expf(lo + (hi - lo) * u1);
    float wc = sqrtf(area * ratio);
    float hc = sqrtf(area / ratio);
    wc = fminf(fmaxf(wc, 1.0f), (float)WW);
    hc = fminf(fmaxf(hc, 1.0f), (float)HH);
    const float fi    = u2 * ((float)HH - hc);
    const float fj    = u3 * ((float)WW - wc);
    const bool  flip  = u4 < 0.5f;
    const float angle = u5 * 3.14159274101257324f;
    const float sigma = 0.1f + 1.9f * u6;

    ImgParams p;
    p.ca = cosf(angle);
    p.sa = sinf(angle);
    const float syk = hc / (float)HH;
    const float sxk = wc / (float)WW;
    p.ay = syk;
    p.by = 0.5f * syk - 0.5f + fi;
    if (flip) {
        p.ax = -sxk;
        p.bx = ((float)WW - 0.5f) * sxk - 0.5f + fj;
    } else {
        p.ax = sxk;
        p.bx = 0.5f * sxk - 0.5f + fj;
    }
    float wk[5], wsum = 0.f;
    const float inv2s2 = 1.0f / (2.0f * sigma * sigma);
    #pragma unroll
    for (int k = 0; k < 5; ++k) {
        float d = (float)k - 2.0f;
        wk[k] = expf(-(d * d) * inv2s2);
        wsum += wk[k];
    }
    float inv = 1.0f / wsum;
    p.w0 = wk[0] * inv; p.w1 = wk[1] * inv; p.w2 = wk[2] * inv;
    p.w3 = wk[3] * inv; p.w4 = wk[4] * inv;
    p.pad = 0.f;
    params[n] = p;
}

__device__ __forceinline__ void swz_decode(int id, int swz, int& unit, int& tile) {
    if (swz) {
        int low  = id & 7;
        int rest = id >> 3;
        int uh   = rest / 49;
        tile     = rest - uh * 49;
        unit     = (uh << 3) | low;
    } else {
        unit = id / 49;
        tile = id - unit * 49;
    }
}

// ---------------- fused: augment section then copy section (r12 structure) ----------------
__global__ __launch_bounds__(256, 8) void fused_kernel(
        const float* __restrict__ M, const int* __restrict__ channel_idx,
        const int* __restrict__ copy_list, const ImgParams* __restrict__ params,
        const float* __restrict__ noise, float* __restrict__ out,
        int c, int n_aug, int n_copy, int aug_blocks, int swz) {
    const int tid = threadIdx.x;
    const int id  = blockIdx.x;

    if (id >= aug_blocks) {
        // -------- copy section: balanced across XCDs by construction --------
        int unit, tile;
        swz_decode(id - aug_blocks, swz, unit, tile);
        const int bi = unit / n_copy;
        const int ci = unit - bi * n_copy;
        const int ch = copy_list[ci];
        const size_t chanoff = ((size_t)bi * c + ch) * (HH * WW);
        const nt_float4* __restrict__ src = (const nt_float4*)(M + chanoff);
        nt_float4* __restrict__ dst = (nt_float4*)(out + chanoff);
        int off = tile * 256 + tid;
        __builtin_nontemporal_store(__builtin_nontemporal_load(&src[off]), &dst[off]);
        return;
    }

    // -------- augment section --------
    int unit, tile;
    swz_decode(id, swz, unit, tile);
    const int bi = unit / n_aug;
    const int a  = unit - bi * n_aug;
    const int ch = channel_idx[a];
    const int n  = unit;                    // bi * n_aug + a
    const size_t chanoff = ((size_t)bi * c + ch) * (HH * WW);

    const int ty = tile / TILES_X;
    const int y0 = ty * TH;
    const int x0 = (tile - ty * TILES_X) * TW;

    const ImgParams P = params[n];          // uniform -> scalar loads
    const float* __restrict__ img = M + chanoff;

    __shared__ __align__(16) float Box[BOXH * BOXW];   // 12.8 KB; aliased as Tmp later
    __shared__ __align__(16) float Wt[HALO][WTS];      // 5.8 KB

    const float cc = 111.5f;

    // ---- bounding box of source coords (block-uniform scalar math) ----
    const int ry_lo = max(y0 - 2, 0),  ry_hi = min(y0 + 33, HH - 1);
    const int rx_lo = max(x0 - 2, 0),  rx_hi = min(x0 + 33, WW - 1);
    const float dyl = (float)ry_lo - cc, dyh = (float)ry_hi - cc;
    const float dxl = (float)rx_lo - cc, dxh = (float)rx_hi - cc;
    float yr_min = cc + fminf(P.ca * dyl, P.ca * dyh) + P.sa * dxl;
    float yr_max = cc + fmaxf(P.ca * dyl, P.ca * dyh) + P.sa * dxh;
    float xr_min = cc + fminf(P.ca * dxl, P.ca * dxh) - P.sa * dyh;
    float xr_max = cc + fmaxf(P.ca * dxl, P.ca * dxh) - P.sa * dyl;
    yr_min = fmaxf(yr_min, -0.5f); yr_max = fminf(yr_max, (float)HH - 0.5f);
    xr_min = fmaxf(xr_min, -0.5f); xr_max = fminf(xr_max, (float)WW - 0.5f);
    const float sy_min = P.ay * yr_min + P.by, sy_max = P.ay * yr_max + P.by;
    const float sx_a = P.ax * xr_min + P.bx,  sx_b = P.ax * xr_max + P.bx;
    const float sx_min = fminf(sx_a, sx_b), sx_max = fmaxf(sx_a, sx_b);
    const int by0 = min(max((int)floorf(sy_min), 0), HH - 1);
    const int by1 = min(max((int)floorf(sy_max) + 1, 0), HH - 1);
    const int bx0 = min(max((int)floorf(sx_min), 0), WW - 1);
    const int bx1 = min(max((int)floorf(sx_max) + 1, 0), WW - 1);
    const int bh = max(by1 - by0 + 1, 0);   // <= 52 rows of real data
    const int bw = bx1 - bx0 + 1;           // <= 52 cols

    // ---- coalesced load of the box into LDS, +1 high-end pad (clamped src) ----
    // Batched: 4 independent global loads in flight, then 4 LDS writes (MLP).
    {
        const int q = tid & 63;
        if (q <= bw) {
            const int scol = min(bx0 + q, WW - 1);
            const float* __restrict__ col = img + scol;
            int r = tid >> 6;
            while (r + 12 <= bh) {
                float a0 = col[min(by0 + r,      HH - 1) * WW];
                float a1 = col[min(by0 + r + 4,  HH - 1) * WW];
                float a2 = col[min(by0 + r + 8,  HH - 1) * WW];
                float a3 = col[min(by0 + r + 12, HH - 1) * WW];
                Box[(r)      * BOXW + q] = a0;
                Box[(r + 4)  * BOXW + q] = a1;
                Box[(r + 8)  * BOXW + q] = a2;
                Box[(r + 12) * BOXW + q] = a3;
                r += 16;
            }
            for (; r <= bh; r += 4)
                Box[r * BOXW + q] = col[min(by0 + r, HH - 1) * WW];
        }
    }
    __syncthreads();

    // ---- warp into halo tile: thread = (row, 6 consecutive x) ----
    // NOTE: per-sample math uses the EXACT reference association
    // (yr = ca*dy + sa*dx + cc, explicit range check) — feeding the
    // discontinuous inb/zero-fill decision; do NOT re-associate (round-6 fail).
    // Restructured into 3-sample batches: addr phase -> read phase -> math phase
    // so ~6 ds_read2 are in flight instead of ~1 (VGPR=20 serialization fix).
    if (tid < 216) {
        const int hy  = tid / 6;
        const int g   = tid - hy * 6;
        const int hx0 = g * 6;
        int vy = y0 + hy - 2;
        int ayv = abs(vy);
        int ry = min(ayv, 2 * (HH - 1) - ayv);   // reflect
        const float dy = (float)ry - cc;
        const int kbase = -(by0 * BOXW + bx0);
        float acc[6];
        #pragma unroll
        for (int h = 0; h < 2; ++h) {
            int kk[3]; float wxv[3], wyv[3]; bool ib[3];
            #pragma unroll
            for (int jj = 0; jj < 3; ++jj) {
                int j = h * 3 + jj;
                int vx = x0 + hx0 + j - 2;
                int axv = abs(vx);
                int rx = min(axv, 2 * (WW - 1) - axv);
                float dx = (float)rx - cc;
                float yr = P.ca * dy + P.sa * dx + cc;
                float xr = P.ca * dx - P.sa * dy + cc;
                bool inb = (yr >= -0.5f && yr <= (float)HH - 0.5f &&
                            xr >= -0.5f && xr <= (float)WW - 0.5f);
                float sy = P.ay * yr + P.by;
                float sx = P.ax * xr + P.bx;
                float fy = floorf(sy), fx = floorf(sx);
                wyv[jj] = sy - fy; wxv[jj] = sx - fx;
                int yi = min(max((int)fy, 0), HH - 1);   // clamp FIRST (ref order)
                int xi = min(max((int)fx, 0), WW - 1);
                int k = yi * BOXW + xi + kbase;
                kk[jj] = inb ? k : 0;                    // uniform flow; masked later
                ib[jj] = inb;
            }
            float v00[3], v01[3], v10[3], v11[3];
            #pragma unroll
            for (int jj = 0; jj < 3; ++jj) {
                v00[jj] = Box[kk[jj]];        v01[jj] = Box[kk[jj] + 1];
                v10[jj] = Box[kk[jj] + BOXW]; v11[jj] = Box[kk[jj] + BOXW + 1];
            }
            #pragma unroll
            for (int jj = 0; jj < 3; ++jj) {
                float top = v00[jj] + (v01[jj] - v00[jj]) * wxv[jj];
                float bot = v10[jj] + (v11[jj] - v10[jj]) * wxv[jj];
                float val = top + (bot - top) * wyv[jj];
                acc[h * 3 + jj] = ib[jj] ? val : 0.f;
            }
        }
        float2* wrow = (float2*)&Wt[hy][hx0];
        wrow[0] = make_float2(acc[0], acc[1]);
        wrow[1] = make_float2(acc[2], acc[3]);
        wrow[2] = make_float2(acc[4], acc[5]);
    }
    __syncthreads();

    // ---- vertical blur: 32 rows x 9 col-quads, float4 ----
    float* __restrict__ Tmp = Box;   // alias; safe after barrier
    for (int u2 = tid; u2 < TH * 9; u2 += 256) {
        int vy2 = u2 / 9, q = u2 - vy2 * 9;
        int x = 4 * q;
        float4 a0 = *(const float4*)&Wt[vy2][x];
        float4 a1 = *(const float4*)&Wt[vy2 + 1][x];
        float4 a2 = *(const float4*)&Wt[vy2 + 2][x];
        float4 a3 = *(const float4*)&Wt[vy2 + 3][x];
        float4 a4 = *(const float4*)&Wt[vy2 + 4][x];
        float4 s;
        s.x = P.w0 * a0.x + P.w1 * a1.x + P.w2 * a2.x + P.w3 * a3.x + P.w4 * a4.x;
        s.y = P.w0 * a0.y + P.w1 * a1.y + P.w2 * a2.y + P.w3 * a3.y + P.w4 * a4.y;
        s.z = P.w0 * a0.z + P.w1 * a1.z + P.w2 * a2.z + P.w3 * a3.z + P.w4 * a4.z;
        s.w = P.w0 * a0.w + P.w1 * a1.w + P.w2 * a2.w + P.w3 * a3.w + P.w4 * a4.w;
        *(float4*)&Tmp[vy2 * TMPS + x] = s;
    }
    __syncthreads();

    // ---- horizontal blur + noise + write, 4 px/thread, float4 ----
    const float* __restrict__ npz = noise + (size_t)n * (HH * WW);
    float* __restrict__ op = out + chanoff;
    {
        int yy = tid >> 3, p = tid & 7;
        int x = 4 * p;
        const float* t = Tmp + yy * TMPS + x;
        float4 ta = *(const float4*)(t);       // t0..t3
        float4 tb = *(const float4*)(t + 4);   // t4..t7
        float s0 = P.w0 * ta.x + P.w1 * ta.y + P.w2 * ta.z + P.w3 * ta.w + P.w4 * tb.x;
        float s1 = P.w0 * ta.y + P.w1 * ta.z + P.w2 * ta.w + P.w3 * tb.x + P.w4 * tb.y;
        float s2 = P.w0 * ta.z + P.w1 * ta.w + P.w2 * tb.x + P.w3 * tb.y + P.w4 * tb.z;
        float s3 = P.w0 * ta.w + P.w1 * tb.x + P.w2 * tb.y + P.w3 * tb.z + P.w4 * tb.w;
        size_t o = (size_t)(y0 + yy) * WW + (x0 + x);
        nt_float4 nz = __builtin_nontemporal_load((const nt_float4*)(npz + o));
        nt_float4 r;
        r.x = s0 + 0.05f * nz.x; r.y = s1 + 0.05f * nz.y;
        r.z = s2 + 0.05f * nz.z; r.w = s3 + 0.05f * nz.w;
        __builtin_nontemporal_store(r, (nt_float4*)(op + o));
    }
}

extern "C" void kernel_launch(void* const* d_in, const int* in_sizes, int n_in,
                              void* d_out, int out_size, void* d_ws, size_t ws_size,
                              hipStream_t stream) {
    const float* M           = (const float*)d_in[0];
    const int*   channel_idx = (const int*)d_in[1];
    const float* aug_u       = (const float*)d_in[2];
    const float* noise       = (const float*)d_in[3];
    float* out = (float*)d_out;

    const int n_aug = in_sizes[1];
    const int b     = in_sizes[2] / (n_aug * 7);
    const int c     = in_sizes[0] / (b * HH * WW);
    const int N     = b * n_aug;
    const int n_copy = c - n_aug;

    int* copy_list = (int*)d_ws;
    int* mark      = (int*)((char*)d_ws + 2048);
    ImgParams* params = (ImgParams*)((char*)d_ws + 8192);

    copylist_kernel<<<1, 256, 0, stream>>>(channel_idx, n_aug, c, copy_list, mark);
    params_kernel<<<(N + 255) / 256, 256, 0, stream>>>(aug_u, params, N);

    const int aug_units  = b * n_aug;
    const int copy_units = b * n_copy;
    const int aug_blocks = 49 * aug_units;
    const int copy_blocks = 49 * copy_units;
    const int swz = (aug_units % 8 == 0 && copy_units % 8 == 0) ? 1 : 0;
    fused_kernel<<<aug_blocks + copy_blocks, 256, 0, stream>>>(
        M, channel_idx, copy_list, params, noise, out,
        c, n_aug, n_copy, aug_blocks, swz);
}

// Round 16
// 220.636 us; speedup vs baseline: 1.2890x; 1.0242x over previous
//
#include <hip/hip_runtime.h>
#include <math.h>

#define HH 224
#define WW 224
#define TH 32
#define TW 32
#define TILES_X 7
#define HALO 36
#define BOXH 56
#define BOXW 57          // LDS stride for the source box (+1 high-end pad)
#define WTS  36          // 144B rows: 16B-aligned, row advance = 1 bank-group (mod 8) -> ~2-way max
#define TMPS 36

typedef float nt_float4 __attribute__((ext_vector_type(4)));  // native vec for nontemporal builtins

struct __align__(16) ImgParams {
    float ca, sa, ay, by;   // rotation + y-affine (sy = ay*yr + by)
    float ax, bx, w0, w1;   // x-affine (flip folded in) + blur taps
    float w2, w3, w4, pad;
};

// ---------------- copy_list: compacted non-augmented channels ----------------
__global__ void copylist_kernel(const int* __restrict__ channel_idx, int n_aug, int c,
                                int* __restrict__ copy_list, int* __restrict__ mark) {
    int t = threadIdx.x;
    for (int i = t; i < c; i += 256) mark[i] = 0;
    __syncthreads();
    for (int i = t; i < n_aug; i += 256) mark[channel_idx[i]] = 1;
    __syncthreads();
    __shared__ int cnt;
    if (t == 0) cnt = 0;
    __syncthreads();
    for (int i = t; i < c; i += 256) {
        if (!mark[i]) {
            int p = atomicAdd(&cnt, 1);
            copy_list[p] = i;
        }
    }
}

// ---------------- per-image params: all transcendentals, once per image ----------------
__global__ void params_kernel(const float* __restrict__ aug_u,
                              ImgParams* __restrict__ params, int N) {
    int n = blockIdx.x * blockDim.x + threadIdx.x;
    if (n >= N) return;
    const float* u = aug_u + (size_t)n * 7;
    const float u0 = u[0], u1 = u[1], u2 = u[2], u3 = u[3], u4 = u[4], u5 = u[5], u6 = u[6];

    const float area  = (float)(HH * WW) * (0.8f + 0.2f * u0);
    const float lo    = logf(0.75f);
    const float hi    = logf(4.0f / 3.0f);
    const float ratio = expf(lo + (hi - lo) * u1);
    float wc = sqrtf(area * ratio);
    float hc = sqrtf(area / ratio);
    wc = fminf(fmaxf(wc, 1.0f), (float)WW);
    hc = fminf(fmaxf(hc, 1.0f), (float)HH);
    const float fi    = u2 * ((float)HH - hc);
    const float fj    = u3 * ((float)WW - wc);
    const bool  flip  = u4 < 0.5f;
    const float angle = u5 * 3.14159274101257324f;
    const float sigma = 0.1f + 1.9f * u6;

    ImgParams p;
    p.ca = cosf(angle);
    p.sa = sinf(angle);
    const float syk = hc / (float)HH;
    const float sxk = wc / (float)WW;
    p.ay = syk;
    p.by = 0.5f * syk - 0.5f + fi;
    if (flip) {
        p.ax = -sxk;
        p.bx = ((float)WW - 0.5f) * sxk - 0.5f + fj;
    } else {
        p.ax = sxk;
        p.bx = 0.5f * sxk - 0.5f + fj;
    }
    float wk[5], wsum = 0.f;
    const float inv2s2 = 1.0f / (2.0f * sigma * sigma);
    #pragma unroll
    for (int k = 0; k < 5; ++k) {
        float d = (float)k - 2.0f;
        wk[k] = expf(-(d * d) * inv2s2);
        wsum += wk[k];
    }
    float inv = 1.0f / wsum;
    p.w0 = wk[0] * inv; p.w1 = wk[1] * inv; p.w2 = wk[2] * inv;
    p.w3 = wk[3] * inv; p.w4 = wk[4] * inv;
    p.pad = 0.f;
    params[n] = p;
}

__device__ __forceinline__ void swz_decode(int id, int swz, int& unit, int& tile) {
    if (swz) {
        int low  = id & 7;
        int rest = id >> 3;
        int uh   = rest / 49;
        tile     = rest - uh * 49;
        unit     = (uh << 3) | low;
    } else {
        unit = id / 49;
        tile = id - unit * 49;
    }
}

// ---------------- fused: augment section then copy section (r12 structure) ----------------
__global__ __launch_bounds__(256) void fused_kernel(
        const float* __restrict__ M, const int* __restrict__ channel_idx,
        const int* __restrict__ copy_list, const ImgParams* __restrict__ params,
        const float* __restrict__ noise, float* __restrict__ out,
        int c, int n_aug, int n_copy, int aug_blocks, int swz) {
    const int tid = threadIdx.x;
    const int id  = blockIdx.x;

    if (id >= aug_blocks) {
        // -------- copy section: balanced across XCDs by construction --------
        int unit, tile;
        swz_decode(id - aug_blocks, swz, unit, tile);
        const int bi = unit / n_copy;
        const int ci = unit - bi * n_copy;
        const int ch = copy_list[ci];
        const size_t chanoff = ((size_t)bi * c + ch) * (HH * WW);
        const nt_float4* __restrict__ src = (const nt_float4*)(M + chanoff);
        nt_float4* __restrict__ dst = (nt_float4*)(out + chanoff);
        int off = tile * 256 + tid;
        __builtin_nontemporal_store(__builtin_nontemporal_load(&src[off]), &dst[off]);
        return;
    }

    // -------- augment section --------
    int unit, tile;
    swz_decode(id, swz, unit, tile);
    const int bi = unit / n_aug;
    const int a  = unit - bi * n_aug;
    const int ch = channel_idx[a];
    const int n  = unit;                    // bi * n_aug + a
    const size_t chanoff = ((size_t)bi * c + ch) * (HH * WW);

    const int ty = tile / TILES_X;
    const int y0 = ty * TH;
    const int x0 = (tile - ty * TILES_X) * TW;

    const ImgParams P = params[n];          // uniform -> scalar loads
    const float* __restrict__ img = M + chanoff;

    __shared__ __align__(16) float Box[BOXH * BOXW];   // 12.8 KB; aliased as Tmp later
    __shared__ __align__(16) float Wt[HALO][WTS];      // 5.1 KB

    const float cc = 111.5f;

    // ---- bounding box of source coords (block-uniform scalar math) ----
    const int ry_lo = max(y0 - 2, 0),  ry_hi = min(y0 + 33, HH - 1);
    const int rx_lo = max(x0 - 2, 0),  rx_hi = min(x0 + 33, WW - 1);
    const float dyl = (float)ry_lo - cc, dyh = (float)ry_hi - cc;
    const float dxl = (float)rx_lo - cc, dxh = (float)rx_hi - cc;
    float yr_min = cc + fminf(P.ca * dyl, P.ca * dyh) + P.sa * dxl;
    float yr_max = cc + fmaxf(P.ca * dyl, P.ca * dyh) + P.sa * dxh;
    float xr_min = cc + fminf(P.ca * dxl, P.ca * dxh) - P.sa * dyh;
    float xr_max = cc + fmaxf(P.ca * dxl, P.ca * dxh) - P.sa * dyl;
    yr_min = fmaxf(yr_min, -0.5f); yr_max = fminf(yr_max, (float)HH - 0.5f);
    xr_min = fmaxf(xr_min, -0.5f); xr_max = fminf(xr_max, (float)WW - 0.5f);
    const float sy_min = P.ay * yr_min + P.by, sy_max = P.ay * yr_max + P.by;
    const float sx_a = P.ax * xr_min + P.bx,  sx_b = P.ax * xr_max + P.bx;
    const float sx_min = fminf(sx_a, sx_b), sx_max = fmaxf(sx_a, sx_b);
    const int by0 = min(max((int)floorf(sy_min), 0), HH - 1);
    const int by1 = min(max((int)floorf(sy_max) + 1, 0), HH - 1);
    const int bx0 = min(max((int)floorf(sx_min), 0), WW - 1);
    const int bx1 = min(max((int)floorf(sx_max) + 1, 0), WW - 1);
    const int bh = max(by1 - by0 + 1, 0);   // <= 52 rows of real data
    const int bw = bx1 - bx0 + 1;           // <= 52 cols

    // ---- coalesced load of the box into LDS, +1 high-end pad (clamped src) ----
    // Reference clamps yi FIRST, then neighbor is yi+1 (re-clamped): per-sample
    // clamp on the low side stays; pad only absorbs the +1 neighbor at 223.
    {
        const int q = tid & 63;
        if (q <= bw) {
            int scol = min(bx0 + q, WW - 1);
            for (int r = tid >> 6; r <= bh; r += 4) {
                int srow = min(by0 + r, HH - 1);
                Box[r * BOXW + q] = img[srow * WW + scol];
            }
        }
    }
    __syncthreads();

    // ---- warp into halo tile: thread = (row, 6 consecutive x) ----
    // NOTE: per-sample math uses the EXACT reference association
    // (yr = ca*dy + sa*dx + cc, explicit range check) — feeding the
    // discontinuous inb/zero-fill decision; do NOT re-associate (round-6 fail).
    if (tid < 216) {
        const int hy  = tid / 6;
        const int g   = tid - hy * 6;
        const int hx0 = g * 6;
        int vy = y0 + hy - 2;
        int ayv = abs(vy);
        int ry = min(ayv, 2 * (HH - 1) - ayv);   // reflect
        const float dy = (float)ry - cc;
        const int kbase = -(by0 * BOXW + bx0);
        float acc[6];
        #pragma unroll
        for (int j = 0; j < 6; ++j) {
            int vx = x0 + hx0 + j - 2;
            int axv = abs(vx);
            int rx = min(axv, 2 * (WW - 1) - axv);
            float dx = (float)rx - cc;
            float yr = P.ca * dy + P.sa * dx + cc;
            float xr = P.ca * dx - P.sa * dy + cc;
            float val = 0.f;
            if (yr >= -0.5f && yr <= (float)HH - 0.5f &&
                xr >= -0.5f && xr <= (float)WW - 0.5f) {
                float sy = P.ay * yr + P.by;
                float sx = P.ax * xr + P.bx;
                float fy = floorf(sy), fx = floorf(sx);
                float wy = sy - fy, wx = sx - fx;
                int yi = min(max((int)fy, 0), HH - 1);   // clamp FIRST (ref order)
                int xi = min(max((int)fx, 0), WW - 1);
                int k = yi * BOXW + xi + kbase;
                float v00 = Box[k],        v01 = Box[k + 1];
                float v10 = Box[k + BOXW], v11 = Box[k + BOXW + 1];
                float top = v00 + (v01 - v00) * wx;
                float bot = v10 + (v11 - v10) * wx;
                val = top + (bot - top) * wy;
            }
            acc[j] = val;
        }
        float2* wrow = (float2*)&Wt[hy][hx0];
        wrow[0] = make_float2(acc[0], acc[1]);
        wrow[1] = make_float2(acc[2], acc[3]);
        wrow[2] = make_float2(acc[4], acc[5]);
    }
    __syncthreads();

    // ---- vertical blur: 32 rows x 9 col-quads, float4 ----
    float* __restrict__ Tmp = Box;   // alias; safe after barrier
    for (int u2 = tid; u2 < TH * 9; u2 += 256) {
        int vy = u2 / 9, q = u2 - vy * 9;
        int x = 4 * q;
        float4 a0 = *(const float4*)&Wt[vy][x];
        float4 a1 = *(const float4*)&Wt[vy + 1][x];
        float4 a2 = *(const float4*)&Wt[vy + 2][x];
        float4 a3 = *(const float4*)&Wt[vy + 3][x];
        float4 a4 = *(const float4*)&Wt[vy + 4][x];
        float4 s;
        s.x = P.w0 * a0.x + P.w1 * a1.x + P.w2 * a2.x + P.w3 * a3.x + P.w4 * a4.x;
        s.y = P.w0 * a0.y + P.w1 * a1.y + P.w2 * a2.y + P.w3 * a3.y + P.w4 * a4.y;
        s.z = P.w0 * a0.z + P.w1 * a1.z + P.w2 * a2.z + P.w3 * a3.z + P.w4 * a4.z;
        s.w = P.w0 * a0.w + P.w1 * a1.w + P.w2 * a2.w + P.w3 * a3.w + P.w4 * a4.w;
        *(float4*)&Tmp[vy * TMPS + x] = s;
    }
    __syncthreads();

    // ---- horizontal blur + noise + write, 4 px/thread, float4 ----
    const float* __restrict__ npz = noise + (size_t)n * (HH * WW);
    float* __restrict__ op = out + chanoff;
    {
        int yy = tid >> 3, p = tid & 7;
        int x = 4 * p;
        const float* t = Tmp + yy * TMPS + x;
        float4 ta = *(const float4*)(t);       // t0..t3
        float4 tb = *(const float4*)(t + 4);   // t4..t7
        float s0 = P.w0 * ta.x + P.w1 * ta.y + P.w2 * ta.z + P.w3 * ta.w + P.w4 * tb.x;
        float s1 = P.w0 * ta.y + P.w1 * ta.z + P.w2 * ta.w + P.w3 * tb.x + P.w4 * tb.y;
        float s2 = P.w0 * ta.z + P.w1 * ta.w + P.w2 * tb.x + P.w3 * tb.y + P.w4 * tb.z;
        float s3 = P.w0 * ta.w + P.w1 * tb.x + P.w2 * tb.y + P.w3 * tb.z + P.w4 * tb.w;
        size_t o = (size_t)(y0 + yy) * WW + (x0 + x);
        nt_float4 nz = __builtin_nontemporal_load((const nt_float4*)(npz + o));
        nt_float4 r;
        r.x = s0 + 0.05f * nz.x; r.y = s1 + 0.05f * nz.y;
        r.z = s2 + 0.05f * nz.z; r.w = s3 + 0.05f * nz.w;
        __builtin_nontemporal_store(r, (nt_float4*)(op + o));
    }
}

extern "C" void kernel_launch(void* const* d_in, const int* in_sizes, int n_in,
                              void* d_out, int out_size, void* d_ws, size_t ws_size,
                              hipStream_t stream) {
    const float* M           = (const float*)d_in[0];
    const int*   channel_idx = (const int*)d_in[1];
    const float* aug_u       = (const float*)d_in[2];
    const float* noise       = (const float*)d_in[3];
    float* out = (float*)d_out;

    const int n_aug = in_sizes[1];
    const int b     = in_sizes[2] / (n_aug * 7);
    const int c     = in_sizes[0] / (b * HH * WW);
    const int N     = b * n_aug;
    const int n_copy = c - n_aug;

    int* copy_list = (int*)d_ws;
    int* mark      = (int*)((char*)d_ws + 2048);
    ImgParams* params = (ImgParams*)((char*)d_ws + 8192);

    copylist_kernel<<<1, 256, 0, stream>>>(channel_idx, n_aug, c, copy_list, mark);
    params_kernel<<<(N + 255) / 256, 256, 0, stream>>>(aug_u, params, N);

    const int aug_units  = b * n_aug;
    const int copy_units = b * n_copy;
    const int aug_blocks = 49 * aug_units;
    const int copy_blocks = 49 * copy_units;
    const int swz = (aug_units % 8 == 0 && copy_units % 8 == 0) ? 1 : 0;
    fused_kernel<<<aug_blocks + copy_blocks, 256, 0, stream>>>(
        M, channel_idx, copy_list, params, noise, out,
        c, n_aug, n_copy, aug_blocks, swz);
}

// Round 17
// 209.924 us; speedup vs baseline: 1.3547x; 1.0510x over previous
//
#include <hip/hip_runtime.h>
#include <math.h>

#define HH 224
#define WW 224
#define TH 32
#define TW 32
#define TILES_X 7
#define HALO 36
#define BOXH 56
#define BOXW 60          // 240B rows: 16B-aligned for b128 LDS writes; granule advance 15 (mod 32)
#define WTS  36          // 144B rows: row advance = 1 bank-group (mod 8) -> ~2-way max (r16 win)
#define TMPS 36

typedef float nt_float4 __attribute__((ext_vector_type(4)));  // native vec for nontemporal builtins

struct __align__(16) ImgParams {
    float ca, sa, ay, by;   // rotation + y-affine (sy = ay*yr + by)
    float ax, bx, w0, w1;   // x-affine (flip folded in) + blur taps
    float w2, w3, w4, pad;
};

// ---------------- copy_list: compacted non-augmented channels ----------------
__global__ void copylist_kernel(const int* __restrict__ channel_idx, int n_aug, int c,
                                int* __restrict__ copy_list, int* __restrict__ mark) {
    int t = threadIdx.x;
    for (int i = t; i < c; i += 256) mark[i] = 0;
    __syncthreads();
    for (int i = t; i < n_aug; i += 256) mark[channel_idx[i]] = 1;
    __syncthreads();
    __shared__ int cnt;
    if (t == 0) cnt = 0;
    __syncthreads();
    for (int i = t; i < c; i += 256) {
        if (!mark[i]) {
            int p = atomicAdd(&cnt, 1);
            copy_list[p] = i;
        }
    }
}

// ---------------- per-image params: all transcendentals, once per image ----------------
__global__ void params_kernel(const float* __restrict__ aug_u,
                              ImgParams* __restrict__ params, int N) {
    int n = blockIdx.x * blockDim.x + threadIdx.x;
    if (n >= N) return;
    const float* u = aug_u + (size_t)n * 7;
    const float u0 = u[0], u1 = u[1], u2 = u[2], u3 = u[3], u4 = u[4], u5 = u[5], u6 = u[6];

    const float area  = (float)(HH * WW) * (0.8f + 0.2f * u0);
    const float lo    = logf(0.75f);
    const float hi    = logf(4.0f / 3.0f);
    const float ratio = expf(lo + (hi - lo) * u1);
    float wc = sqrtf(area * ratio);
    float hc = sqrtf(area / ratio);
    wc = fminf(fmaxf(wc, 1.0f), (float)WW);
    hc = fminf(fmaxf(hc, 1.0f), (float)HH);
    const float fi    = u2 * ((float)HH - hc);
    const float fj    = u3 * ((float)WW - wc);
    const bool  flip  = u4 < 0.5f;
    const float angle = u5 * 3.14159274101257324f;
    const float sigma = 0.1f + 1.9f * u6;

    ImgParams p;
    p.ca = cosf(angle);
    p.sa = sinf(angle);
    const float syk = hc / (float)HH;
    const float sxk = wc / (float)WW;
    p.ay = syk;
    p.by = 0.5f * syk - 0.5f + fi;
    if (flip) {
        p.ax = -sxk;
        p.bx = ((float)WW - 0.5f) * sxk - 0.5f + fj;
    } else {
        p.ax = sxk;
        p.bx = 0.5f * sxk - 0.5f + fj;
    }
    float wk[5], wsum = 0.f;
    const float inv2s2 = 1.0f / (2.0f * sigma * sigma);
    #pragma unroll
    for (int k = 0; k < 5; ++k) {
        float d = (float)k - 2.0f;
        wk[k] = expf(-(d * d) * inv2s2);
        wsum += wk[k];
    }
    float inv = 1.0f / wsum;
    p.w0 = wk[0] * inv; p.w1 = wk[1] * inv; p.w2 = wk[2] * inv;
    p.w3 = wk[3] * inv; p.w4 = wk[4] * inv;
    p.pad = 0.f;
    params[n] = p;
}

__device__ __forceinline__ void swz_decode(int id, int swz, int& unit, int& tile) {
    if (swz) {
        int low  = id & 7;
        int rest = id >> 3;
        int uh   = rest / 49;
        tile     = rest - uh * 49;
        unit     = (uh << 3) | low;
    } else {
        unit = id / 49;
        tile = id - unit * 49;
    }
}

// ---------------- fused: augment section then copy section (r12/r16 structure) ----------------
__global__ __launch_bounds__(256) void fused_kernel(
        const float* __restrict__ M, const int* __restrict__ channel_idx,
        const int* __restrict__ copy_list, const ImgParams* __restrict__ params,
        const float* __restrict__ noise, float* __restrict__ out,
        int c, int n_aug, int n_copy, int aug_blocks, int swz) {
    const int tid = threadIdx.x;
    const int id  = blockIdx.x;

    if (id >= aug_blocks) {
        // -------- copy section: balanced across XCDs by construction --------
        int unit, tile;
        swz_decode(id - aug_blocks, swz, unit, tile);
        const int bi = unit / n_copy;
        const int ci = unit - bi * n_copy;
        const int ch = copy_list[ci];
        const size_t chanoff = ((size_t)bi * c + ch) * (HH * WW);
        const nt_float4* __restrict__ src = (const nt_float4*)(M + chanoff);
        nt_float4* __restrict__ dst = (nt_float4*)(out + chanoff);
        int off = tile * 256 + tid;
        __builtin_nontemporal_store(__builtin_nontemporal_load(&src[off]), &dst[off]);
        return;
    }

    // -------- augment section --------
    int unit, tile;
    swz_decode(id, swz, unit, tile);
    const int bi = unit / n_aug;
    const int a  = unit - bi * n_aug;
    const int ch = channel_idx[a];
    const int n  = unit;                    // bi * n_aug + a
    const size_t chanoff = ((size_t)bi * c + ch) * (HH * WW);

    const int ty = tile / TILES_X;
    const int tx = tile - ty * TILES_X;
    const int y0 = ty * TH;
    const int x0 = tx * TW;
    const bool refl = (ty == 0) || (ty == 6) || (tx == 0) || (tx == 6);  // block-uniform

    const ImgParams P = params[n];          // uniform -> scalar loads
    const float* __restrict__ img = M + chanoff;

    __shared__ __align__(16) float Box[BOXH * BOXW];   // 13.4 KB; aliased as Tmp later
    __shared__ __align__(16) float Wt[HALO][WTS];      // 5.1 KB

    const float cc = 111.5f;

    // ---- bounding box of source coords (block-uniform scalar math) ----
    const int ry_lo = max(y0 - 2, 0),  ry_hi = min(y0 + 33, HH - 1);
    const int rx_lo = max(x0 - 2, 0),  rx_hi = min(x0 + 33, WW - 1);
    const float dyl = (float)ry_lo - cc, dyh = (float)ry_hi - cc;
    const float dxl = (float)rx_lo - cc, dxh = (float)rx_hi - cc;
    float yr_min = cc + fminf(P.ca * dyl, P.ca * dyh) + P.sa * dxl;
    float yr_max = cc + fmaxf(P.ca * dyl, P.ca * dyh) + P.sa * dxh;
    float xr_min = cc + fminf(P.ca * dxl, P.ca * dxh) - P.sa * dyh;
    float xr_max = cc + fmaxf(P.ca * dxl, P.ca * dxh) - P.sa * dyl;
    yr_min = fmaxf(yr_min, -0.5f); yr_max = fminf(yr_max, (float)HH - 0.5f);
    xr_min = fmaxf(xr_min, -0.5f); xr_max = fminf(xr_max, (float)WW - 0.5f);
    const float sy_min = P.ay * yr_min + P.by, sy_max = P.ay * yr_max + P.by;
    const float sx_a = P.ax * xr_min + P.bx,  sx_b = P.ax * xr_max + P.bx;
    const float sx_min = fminf(sx_a, sx_b), sx_max = fmaxf(sx_a, sx_b);
    const int by0 = min(max((int)floorf(sy_min), 0), HH - 1);
    const int by1 = min(max((int)floorf(sy_max) + 1, 0), HH - 1);
    const int bx0 = min(max((int)floorf(sx_min), 0), WW - 1);
    const int bx1 = min(max((int)floorf(sx_max) + 1, 0), WW - 1);
    const int bh = max(by1 - by0 + 1, 0);   // <= 52 rows of real data (+1 pad row via clamp)

    // ---- float4 box staging: aligned columns, b128 LDS writes ----
    // abx0 = bx0 rounded down to float4; rows srow-clamped (covers the +1 pad row).
    // Pad COLUMN (bx1==223 -> dup of col 223) fixed in a uniform pass below.
    const int abx0  = bx0 & ~3;
    const int relw  = bx1 + 2 - abx0;                       // cols incl. +1 pad col
    const int ncols4 = min((relw + 3) >> 2, (WW - abx0) >> 2);
    {
        const int c4 = tid & 15;                            // 16 float4 columns
        if (c4 < ncols4) {
            const int scolb = abx0 + 4 * c4;
            for (int r = tid >> 4; r <= bh; r += 16) {
                int srow = min(by0 + r, HH - 1);
                nt_float4 v = *(const nt_float4*)(img + srow * WW + scolb);
                *(nt_float4*)&Box[r * BOXW + 4 * c4] = v;
            }
        }
    }
    __syncthreads();
    if (bx1 == WW - 1) {                                    // block-uniform
        for (int r = tid; r <= bh; r += 256)
            Box[r * BOXW + (WW - abx0)] = Box[r * BOXW + (WW - 1 - abx0)];
    }
    __syncthreads();

    // ---- warp into halo tile: thread = (row, 6 consecutive x) ----
    // NOTE: per-sample math uses the EXACT reference association
    // (yr = ca*dy + sa*dx + cc, explicit range check) — feeding the
    // discontinuous inb/zero-fill decision; do NOT re-associate (round-6 fail).
    // REFL is a literal: interior tiles skip the reflect abs/min entirely.
#define WARP_SAMPLES(REFL)                                                     \
    {                                                                          \
        int ry;                                                                \
        if (REFL) { int ayv = abs(vy); ry = min(ayv, 2 * (HH - 1) - ayv); }    \
        else ry = vy;                                                          \
        const float dy = (float)ry - cc;                                       \
        _Pragma("unroll")                                                      \
        for (int j = 0; j < 6; ++j) {                                          \
            int vx = x0 + hx0 + j - 2;                                         \
            int rx;                                                            \
            if (REFL) { int axv = abs(vx); rx = min(axv, 2 * (WW - 1) - axv); }\
            else rx = vx;                                                      \
            float dx = (float)rx - cc;                                         \
            float yr = P.ca * dy + P.sa * dx + cc;                             \
            float xr = P.ca * dx - P.sa * dy + cc;                             \
            float val = 0.f;                                                   \
            if (yr >= -0.5f && yr <= (float)HH - 0.5f &&                       \
                xr >= -0.5f && xr <= (float)WW - 0.5f) {                       \
                float sy = P.ay * yr + P.by;                                   \
                float sx = P.ax * xr + P.bx;                                   \
                float fy = floorf(sy), fx = floorf(sx);                        \
                float wy = sy - fy, wx = sx - fx;                              \
                int yi = min(max((int)fy, 0), HH - 1);  /* clamp FIRST */      \
                int xi = min(max((int)fx, 0), WW - 1);                         \
                int k = yi * BOXW + xi + kbase;                                \
                float v00 = Box[k],        v01 = Box[k + 1];                   \
                float v10 = Box[k + BOXW], v11 = Box[k + BOXW + 1];            \
                float top = v00 + (v01 - v00) * wx;                            \
                float bot = v10 + (v11 - v10) * wx;                            \
                val = top + (bot - top) * wy;                                  \
            }                                                                  \
            acc[j] = val;                                                      \
        }                                                                      \
    }

    if (tid < 216) {
        const int hy  = tid / 6;
        const int g   = tid - hy * 6;
        const int hx0 = g * 6;
        const int vy  = y0 + hy - 2;
        const int kbase = -(by0 * BOXW + abx0);
        float acc[6];
        if (refl) WARP_SAMPLES(1) else WARP_SAMPLES(0)
        float2* wrow = (float2*)&Wt[hy][hx0];
        wrow[0] = make_float2(acc[0], acc[1]);
        wrow[1] = make_float2(acc[2], acc[3]);
        wrow[2] = make_float2(acc[4], acc[5]);
    }
#undef WARP_SAMPLES
    __syncthreads();

    // ---- vertical blur: 32 rows x 9 col-quads, float4 ----
    float* __restrict__ Tmp = Box;   // alias; safe after barrier
    for (int u2 = tid; u2 < TH * 9; u2 += 256) {
        int vy2 = u2 / 9, q = u2 - vy2 * 9;
        int x = 4 * q;
        float4 a0 = *(const float4*)&Wt[vy2][x];
        float4 a1 = *(const float4*)&Wt[vy2 + 1][x];
        float4 a2 = *(const float4*)&Wt[vy2 + 2][x];
        float4 a3 = *(const float4*)&Wt[vy2 + 3][x];
        float4 a4 = *(const float4*)&Wt[vy2 + 4][x];
        float4 s;
        s.x = P.w0 * a0.x + P.w1 * a1.x + P.w2 * a2.x + P.w3 * a3.x + P.w4 * a4.x;
        s.y = P.w0 * a0.y + P.w1 * a1.y + P.w2 * a2.y + P.w3 * a3.y + P.w4 * a4.y;
        s.z = P.w0 * a0.z + P.w1 * a1.z + P.w2 * a2.z + P.w3 * a3.z + P.w4 * a4.z;
        s.w = P.w0 * a0.w + P.w1 * a1.w + P.w2 * a2.w + P.w3 * a3.w + P.w4 * a4.w;
        *(float4*)&Tmp[vy2 * TMPS + x] = s;
    }
    __syncthreads();

    // ---- horizontal blur + noise + write, 4 px/thread, float4 ----
    const float* __restrict__ npz = noise + (size_t)n * (HH * WW);
    float* __restrict__ op = out + chanoff;
    {
        int yy = tid >> 3, p = tid & 7;
        int x = 4 * p;
        const float* t = Tmp + yy * TMPS + x;
        float4 ta = *(const float4*)(t);       // t0..t3
        float4 tb = *(const float4*)(t + 4);   // t4..t7
        float s0 = P.w0 * ta.x + P.w1 * ta.y + P.w2 * ta.z + P.w3 * ta.w + P.w4 * tb.x;
        float s1 = P.w0 * ta.y + P.w1 * ta.z + P.w2 * ta.w + P.w3 * tb.x + P.w4 * tb.y;
        float s2 = P.w0 * ta.z + P.w1 * ta.w + P.w2 * tb.x + P.w3 * tb.y + P.w4 * tb.z;
        float s3 = P.w0 * ta.w + P.w1 * tb.x + P.w2 * tb.y + P.w3 * tb.z + P.w4 * tb.w;
        size_t o = (size_t)(y0 + yy) * WW + (x0 + x);
        nt_float4 nz = __builtin_nontemporal_load((const nt_float4*)(npz + o));
        nt_float4 r;
        r.x = s0 + 0.05f * nz.x; r.y = s1 + 0.05f * nz.y;
        r.z = s2 + 0.05f * nz.z; r.w = s3 + 0.05f * nz.w;
        __builtin_nontemporal_store(r, (nt_float4*)(op + o));
    }
}

extern "C" void kernel_launch(void* const* d_in, const int* in_sizes, int n_in,
                              void* d_out, int out_size, void* d_ws, size_t ws_size,
                              hipStream_t stream) {
    const float* M           = (const float*)d_in[0];
    const int*   channel_idx = (const int*)d_in[1];
    const float* aug_u       = (const float*)d_in[2];
    const float* noise       = (const float*)d_in[3];
    float* out = (float*)d_out;

    const int n_aug = in_sizes[1];
    const int b     = in_sizes[2] / (n_aug * 7);
    const int c     = in_sizes[0] / (b * HH * WW);
    const int N     = b * n_aug;
    const int n_copy = c - n_aug;

    int* copy_list = (int*)d_ws;
    int* mark      = (int*)((char*)d_ws + 2048);
    ImgParams* params = (ImgParams*)((char*)d_ws + 8192);

    copylist_kernel<<<1, 256, 0, stream>>>(channel_idx, n_aug, c, copy_list, mark);
    params_kernel<<<(N + 255) / 256, 256, 0, stream>>>(aug_u, params, N);

    const int aug_units  = b * n_aug;
    const int copy_units = b * n_copy;
    const int aug_blocks = 49 * aug_units;
    const int copy_blocks = 49 * copy_units;
    const int swz = (aug_units % 8 == 0 && copy_units % 8 == 0) ? 1 : 0;
    fused_kernel<<<aug_blocks + copy_blocks, 256, 0, stream>>>(
        M, channel_idx, copy_list, params, noise, out,
        c, n_aug, n_copy, aug_blocks, swz);
}

// Round 18
// 207.841 us; speedup vs baseline: 1.3683x; 1.0100x over previous
//
#include <hip/hip_runtime.h>
#include <math.h>

#define HH 224
#define WW 224
#define TH 32
#define TW 32
#define TILES_X 7
#define HALO 36
#define BOXH 56
#define BOXW 60          // 240B rows: 16B-aligned for b128 LDS writes; granule advance 15 (mod 32)
#define WTS  36          // 144B rows: row advance = 1 bank-group (mod 8) -> ~2-way max (r16 win)
#define TMPS 36

typedef float nt_float4 __attribute__((ext_vector_type(4)));  // native vec for nontemporal builtins

struct __align__(16) ImgParams {
    float ca, sa, ay, by;   // rotation + y-affine (sy = ay*yr + by)
    float ax, bx, w0, w1;   // x-affine (flip folded in) + blur taps
    float w2, w3, w4, pad;
};

// ---------------- copy_list: compacted non-augmented channels ----------------
__global__ void copylist_kernel(const int* __restrict__ channel_idx, int n_aug, int c,
                                int* __restrict__ copy_list, int* __restrict__ mark) {
    int t = threadIdx.x;
    for (int i = t; i < c; i += 256) mark[i] = 0;
    __syncthreads();
    for (int i = t; i < n_aug; i += 256) mark[channel_idx[i]] = 1;
    __syncthreads();
    __shared__ int cnt;
    if (t == 0) cnt = 0;
    __syncthreads();
    for (int i = t; i < c; i += 256) {
        if (!mark[i]) {
            int p = atomicAdd(&cnt, 1);
            copy_list[p] = i;
        }
    }
}

// ---------------- per-image params: all transcendentals, once per image ----------------
__global__ void params_kernel(const float* __restrict__ aug_u,
                              ImgParams* __restrict__ params, int N) {
    int n = blockIdx.x * blockDim.x + threadIdx.x;
    if (n >= N) return;
    const float* u = aug_u + (size_t)n * 7;
    const float u0 = u[0], u1 = u[1], u2 = u[2], u3 = u[3], u4 = u[4], u5 = u[5], u6 = u[6];

    const float area  = (float)(HH * WW) * (0.8f + 0.2f * u0);
    const float lo    = logf(0.75f);
    const float hi    = logf(4.0f / 3.0f);
    const float ratio = expf(lo + (hi - lo) * u1);
    float wc = sqrtf(area * ratio);
    float hc = sqrtf(area / ratio);
    wc = fminf(fmaxf(wc, 1.0f), (float)WW);
    hc = fminf(fmaxf(hc, 1.0f), (float)HH);
    const float fi    = u2 * ((float)HH - hc);
    const float fj    = u3 * ((float)WW - wc);
    const bool  flip  = u4 < 0.5f;
    const float angle = u5 * 3.14159274101257324f;
    const float sigma = 0.1f + 1.9f * u6;

    ImgParams p;
    p.ca = cosf(angle);
    p.sa = sinf(angle);
    const float syk = hc / (float)HH;
    const float sxk = wc / (float)WW;
    p.ay = syk;
    p.by = 0.5f * syk - 0.5f + fi;
    if (flip) {
        p.ax = -sxk;
        p.bx = ((float)WW - 0.5f) * sxk - 0.5f + fj;
    } else {
        p.ax = sxk;
        p.bx = 0.5f * sxk - 0.5f + fj;
    }
    float wk[5], wsum = 0.f;
    const float inv2s2 = 1.0f / (2.0f * sigma * sigma);
    #pragma unroll
    for (int k = 0; k < 5; ++k) {
        float d = (float)k - 2.0f;
        wk[k] = expf(-(d * d) * inv2s2);
        wsum += wk[k];
    }
    float inv = 1.0f / wsum;
    p.w0 = wk[0] * inv; p.w1 = wk[1] * inv; p.w2 = wk[2] * inv;
    p.w3 = wk[3] * inv; p.w4 = wk[4] * inv;
    p.pad = 0.f;
    params[n] = p;
}

__device__ __forceinline__ void swz_decode(int id, int swz, int& unit, int& tile) {
    if (swz) {
        int low  = id & 7;
        int rest = id >> 3;
        int uh   = rest / 49;
        tile     = rest - uh * 49;
        unit     = (uh << 3) | low;
    } else {
        unit = id / 49;
        tile = id - unit * 49;
    }
}

// ---------------- fused: augment section then copy section ----------------
__global__ __launch_bounds__(256) void fused_kernel(
        const float* __restrict__ M, const int* __restrict__ channel_idx,
        const int* __restrict__ copy_list, const ImgParams* __restrict__ params,
        const float* __restrict__ noise, float* __restrict__ out,
        int c, int n_aug, int n_copy, int aug_blocks, int swz) {
    const int tid = threadIdx.x;
    const int id  = blockIdx.x;

    if (id >= aug_blocks) {
        // -------- copy section: balanced across XCDs by construction --------
        int unit, tile;
        swz_decode(id - aug_blocks, swz, unit, tile);
        const int bi = unit / n_copy;
        const int ci = unit - bi * n_copy;
        const int ch = copy_list[ci];
        const size_t chanoff = ((size_t)bi * c + ch) * (HH * WW);
        const nt_float4* __restrict__ src = (const nt_float4*)(M + chanoff);
        nt_float4* __restrict__ dst = (nt_float4*)(out + chanoff);
        int off = tile * 256 + tid;
        __builtin_nontemporal_store(__builtin_nontemporal_load(&src[off]), &dst[off]);
        return;
    }

    // -------- augment section --------
    int unit, tile;
    swz_decode(id, swz, unit, tile);
    const int bi = unit / n_aug;
    const int a  = unit - bi * n_aug;
    const int ch = channel_idx[a];
    const int n  = unit;                    // bi * n_aug + a
    const size_t chanoff = ((size_t)bi * c + ch) * (HH * WW);

    const int ty = tile / TILES_X;
    const int tx = tile - ty * TILES_X;
    const int y0 = ty * TH;
    const int x0 = tx * TW;
    const bool refl = (ty == 0) || (ty == 6) || (tx == 0) || (tx == 6);  // block-uniform

    const ImgParams P = params[n];          // uniform -> scalar loads
    const float* __restrict__ img = M + chanoff;

    __shared__ __align__(16) float Box[BOXH * BOXW];   // 13.4 KB; aliased as Tmp later
    __shared__ __align__(16) float Wt[HALO][WTS];      // 5.1 KB

    const float cc = 111.5f;

    // ---- bounding box of source coords (block-uniform scalar math) ----
    const int ry_lo = max(y0 - 2, 0),  ry_hi = min(y0 + 33, HH - 1);
    const int rx_lo = max(x0 - 2, 0),  rx_hi = min(x0 + 33, WW - 1);
    const float dyl = (float)ry_lo - cc, dyh = (float)ry_hi - cc;
    const float dxl = (float)rx_lo - cc, dxh = (float)rx_hi - cc;
    float yr_min = cc + fminf(P.ca * dyl, P.ca * dyh) + P.sa * dxl;
    float yr_max = cc + fmaxf(P.ca * dyl, P.ca * dyh) + P.sa * dxh;
    float xr_min = cc + fminf(P.ca * dxl, P.ca * dxh) - P.sa * dyh;
    float xr_max = cc + fmaxf(P.ca * dxl, P.ca * dxh) - P.sa * dyl;
    // fully-in-bounds test on RAW bounds, conservative eps (0.01 >> fma ulp accum):
    // only SKIPS the per-sample check when its outcome is certain — never re-associated.
    const bool inball = (yr_min >= -0.49f) && (yr_max <= (float)HH - 0.51f) &&
                        (xr_min >= -0.49f) && (xr_max <= (float)WW - 0.51f);
    yr_min = fmaxf(yr_min, -0.5f); yr_max = fminf(yr_max, (float)HH - 0.5f);
    xr_min = fmaxf(xr_min, -0.5f); xr_max = fminf(xr_max, (float)WW - 0.5f);
    const float sy_min = P.ay * yr_min + P.by, sy_max = P.ay * yr_max + P.by;
    const float sx_a = P.ax * xr_min + P.bx,  sx_b = P.ax * xr_max + P.bx;
    const float sx_min = fminf(sx_a, sx_b), sx_max = fmaxf(sx_a, sx_b);
    const int by0 = min(max((int)floorf(sy_min), 0), HH - 1);
    const int by1 = min(max((int)floorf(sy_max) + 1, 0), HH - 1);
    const int bx0 = min(max((int)floorf(sx_min), 0), WW - 1);
    const int bx1 = min(max((int)floorf(sx_max) + 1, 0), WW - 1);
    const int bh = max(by1 - by0 + 1, 0);   // <= 52 rows of real data (+1 pad row via clamp)

    // ---- float4 box staging: aligned columns, b128 LDS writes ----
    const int abx0  = bx0 & ~3;
    const int relw  = bx1 + 2 - abx0;                       // cols incl. +1 pad col
    const int ncols4 = min((relw + 3) >> 2, (WW - abx0) >> 2);
    {
        const int c4 = tid & 15;                            // 16 float4 columns
        if (c4 < ncols4) {
            const int scolb = abx0 + 4 * c4;
            for (int r = tid >> 4; r <= bh; r += 16) {
                int srow = min(by0 + r, HH - 1);
                nt_float4 v = *(const nt_float4*)(img + srow * WW + scolb);
                *(nt_float4*)&Box[r * BOXW + 4 * c4] = v;
            }
        }
    }
    // pad COLUMN (bx1==223): dup col 223, read from img directly -> no extra barrier
    if (bx1 == WW - 1) {                                    // block-uniform
        for (int r = tid; r <= bh; r += 256) {
            int srow = min(by0 + r, HH - 1);
            Box[r * BOXW + (WW - abx0)] = img[srow * WW + (WW - 1)];
        }
    }
    __syncthreads();

    // ---- warp into halo tile: thread = (row, 6 consecutive x) ----
    // NOTE: per-sample math uses the EXACT reference association
    // (yr = ca*dy + sa*dx + cc, explicit range check) — feeding the
    // discontinuous inb/zero-fill decision; do NOT re-associate (round-6 fail).
    // REFL/INB are literals: interior tiles skip reflect; fully-inb tiles skip the check.
#define WARP_SAMPLES(REFL, INB)                                                \
    {                                                                          \
        int ry;                                                                \
        if (REFL) { int ayv = abs(vy); ry = min(ayv, 2 * (HH - 1) - ayv); }    \
        else ry = vy;                                                          \
        const float dy = (float)ry - cc;                                       \
        _Pragma("unroll")                                                      \
        for (int j = 0; j < 6; ++j) {                                          \
            int vx = x0 + hx0 + j - 2;                                         \
            int rx;                                                            \
            if (REFL) { int axv = abs(vx); rx = min(axv, 2 * (WW - 1) - axv); }\
            else rx = vx;                                                      \
            float dx = (float)rx - cc;                                         \
            float yr = P.ca * dy + P.sa * dx + cc;                             \
            float xr = P.ca * dx - P.sa * dy + cc;                             \
            float val = 0.f;                                                   \
            if (INB || (yr >= -0.5f && yr <= (float)HH - 0.5f &&               \
                        xr >= -0.5f && xr <= (float)WW - 0.5f)) {              \
                float sy = P.ay * yr + P.by;                                   \
                float sx = P.ax * xr + P.bx;                                   \
                float fy = floorf(sy), fx = floorf(sx);                        \
                float wy = sy - fy, wx = sx - fx;                              \
                int yi = min(max((int)fy, 0), HH - 1);  /* clamp FIRST */      \
                int xi = min(max((int)fx, 0), WW - 1);                         \
                int k = yi * BOXW + xi + kbase;                                \
                float v00 = Box[k],        v01 = Box[k + 1];                   \
                float v10 = Box[k + BOXW], v11 = Box[k + BOXW + 1];            \
                float top = v00 + (v01 - v00) * wx;                            \
                float bot = v10 + (v11 - v10) * wx;                            \
                val = top + (bot - top) * wy;                                  \
            }                                                                  \
            acc[j] = val;                                                      \
        }                                                                      \
    }

    if (tid < 216) {
        const int hy  = tid / 6;
        const int g   = tid - hy * 6;
        const int hx0 = g * 6;
        const int vy  = y0 + hy - 2;
        const int kbase = -(by0 * BOXW + abx0);
        float acc[6];
        if (refl) {
            if (inball) WARP_SAMPLES(1, 1) else WARP_SAMPLES(1, 0)
        } else {
            if (inball) WARP_SAMPLES(0, 1) else WARP_SAMPLES(0, 0)
        }
        float2* wrow = (float2*)&Wt[hy][hx0];
        wrow[0] = make_float2(acc[0], acc[1]);
        wrow[1] = make_float2(acc[2], acc[3]);
        wrow[2] = make_float2(acc[4], acc[5]);
    }
#undef WARP_SAMPLES
    __syncthreads();

    // ---- vertical blur: 32 rows x 9 col-quads, float4 ----
    float* __restrict__ Tmp = Box;   // alias; safe after barrier
    for (int u2 = tid; u2 < TH * 9; u2 += 256) {
        int vy2 = u2 / 9, q = u2 - vy2 * 9;
        int x = 4 * q;
        float4 a0 = *(const float4*)&Wt[vy2][x];
        float4 a1 = *(const float4*)&Wt[vy2 + 1][x];
        float4 a2 = *(const float4*)&Wt[vy2 + 2][x];
        float4 a3 = *(const float4*)&Wt[vy2 + 3][x];
        float4 a4 = *(const float4*)&Wt[vy2 + 4][x];
        float4 s;
        s.x = P.w0 * a0.x + P.w1 * a1.x + P.w2 * a2.x + P.w3 * a3.x + P.w4 * a4.x;
        s.y = P.w0 * a0.y + P.w1 * a1.y + P.w2 * a2.y + P.w3 * a3.y + P.w4 * a4.y;
        s.z = P.w0 * a0.z + P.w1 * a1.z + P.w2 * a2.z + P.w3 * a3.z + P.w4 * a4.z;
        s.w = P.w0 * a0.w + P.w1 * a1.w + P.w2 * a2.w + P.w3 * a3.w + P.w4 * a4.w;
        *(float4*)&Tmp[vy2 * TMPS + x] = s;
    }
    __syncthreads();

    // ---- horizontal blur + noise + write, 4 px/thread, float4 ----
    const float* __restrict__ npz = noise + (size_t)n * (HH * WW);
    float* __restrict__ op = out + chanoff;
    {
        int yy = tid >> 3, p = tid & 7;
        int x = 4 * p;
        const float* t = Tmp + yy * TMPS + x;
        float4 ta = *(const float4*)(t);       // t0..t3
        float4 tb = *(const float4*)(t + 4);   // t4..t7
        float s0 = P.w0 * ta.x + P.w1 * ta.y + P.w2 * ta.z + P.w3 * ta.w + P.w4 * tb.x;
        float s1 = P.w0 * ta.y + P.w1 * ta.z + P.w2 * ta.w + P.w3 * tb.x + P.w4 * tb.y;
        float s2 = P.w0 * ta.z + P.w1 * ta.w + P.w2 * tb.x + P.w3 * tb.y + P.w4 * tb.z;
        float s3 = P.w0 * ta.w + P.w1 * tb.x + P.w2 * tb.y + P.w3 * tb.z + P.w4 * tb.w;
        size_t o = (size_t)(y0 + yy) * WW + (x0 + x);
        nt_float4 nz = __builtin_nontemporal_load((const nt_float4*)(npz + o));
        nt_float4 r;
        r.x = s0 + 0.05f * nz.x; r.y = s1 + 0.05f * nz.y;
        r.z = s2 + 0.05f * nz.z; r.w = s3 + 0.05f * nz.w;
        __builtin_nontemporal_store(r, (nt_float4*)(op + o));
    }
}

extern "C" void kernel_launch(void* const* d_in, const int* in_sizes, int n_in,
                              void* d_out, int out_size, void* d_ws, size_t ws_size,
                              hipStream_t stream) {
    const float* M           = (const float*)d_in[0];
    const int*   channel_idx = (const int*)d_in[1];
    const float* aug_u       = (const float*)d_in[2];
    const float* noise       = (const float*)d_in[3];
    float* out = (float*)d_out;

    const int n_aug = in_sizes[1];
    const int b     = in_sizes[2] / (n_aug * 7);
    const int c     = in_sizes[0] / (b * HH * WW);
    const int N     = b * n_aug;
    const int n_copy = c - n_aug;

    int* copy_list = (int*)d_ws;
    int* mark      = (int*)((char*)d_ws + 2048);
    ImgParams* params = (ImgParams*)((char*)d_ws + 8192);

    copylist_kernel<<<1, 256, 0, stream>>>(channel_idx, n_aug, c, copy_list, mark);
    params_kernel<<<(N + 255) / 256, 256, 0, stream>>>(aug_u, params, N);

    const int aug_units  = b * n_aug;
    const int copy_units = b * n_copy;
    const int aug_blocks = 49 * aug_units;
    const int copy_blocks = 49 * copy_units;
    const int swz = (aug_units % 8 == 0 && copy_units % 8 == 0) ? 1 : 0;
    fused_kernel<<<aug_blocks + copy_blocks, 256, 0, stream>>>(
        M, channel_idx, copy_list, params, noise, out,
        c, n_aug, n_copy, aug_blocks, swz);
}

// Round 19
// 204.552 us; speedup vs baseline: 1.3903x; 1.0161x over previous
//
#include <hip/hip_runtime.h>
#include <math.h>

#define HH 224
#define WW 224
#define TH 32
#define TW 32
#define TILES_X 7
#define HALO 36
#define BOXH 56
#define BOXW 60          // 240B rows: 16B-aligned for b128 LDS writes; granule advance 15 (mod 32)
#define WTS  36          // 144B rows: row advance = 1 bank-group (mod 8) -> ~2-way max (r16 win)
#define TMPS 36

typedef float nt_float4 __attribute__((ext_vector_type(4)));  // native vec for nontemporal builtins

struct __align__(16) ImgParams {
    float ca, sa, ay, by;   // rotation + y-affine (sy = ay*yr + by)
    float ax, bx, w0, w1;   // x-affine (flip folded in) + blur taps
    float w2, w3, w4, pad;
};

// ---------------- setup: copy_list (block 0) + per-image params (blocks 1..) ----------------
__global__ void setup_kernel(const int* __restrict__ channel_idx, int n_aug, int c,
                             int* __restrict__ copy_list, int* __restrict__ mark,
                             const float* __restrict__ aug_u,
                             ImgParams* __restrict__ params, int N) {
    if (blockIdx.x == 0) {
        int t = threadIdx.x;
        for (int i = t; i < c; i += 256) mark[i] = 0;
        __syncthreads();
        for (int i = t; i < n_aug; i += 256) mark[channel_idx[i]] = 1;
        __syncthreads();
        __shared__ int cnt;
        if (t == 0) cnt = 0;
        __syncthreads();
        for (int i = t; i < c; i += 256) {
            if (!mark[i]) {
                int p = atomicAdd(&cnt, 1);
                copy_list[p] = i;
            }
        }
        return;
    }
    int n = (blockIdx.x - 1) * blockDim.x + threadIdx.x;
    if (n >= N) return;
    const float* u = aug_u + (size_t)n * 7;
    const float u0 = u[0], u1 = u[1], u2 = u[2], u3 = u[3], u4 = u[4], u5 = u[5], u6 = u[6];

    const float area  = (float)(HH * WW) * (0.8f + 0.2f * u0);
    const float lo    = logf(0.75f);
    const float hi    = logf(4.0f / 3.0f);
    const float ratio = expf(lo + (hi - lo) * u1);
    float wc = sqrtf(area * ratio);
    float hc = sqrtf(area / ratio);
    wc = fminf(fmaxf(wc, 1.0f), (float)WW);
    hc = fminf(fmaxf(hc, 1.0f), (float)HH);
    const float fi    = u2 * ((float)HH - hc);
    const float fj    = u3 * ((float)WW - wc);
    const bool  flip  = u4 < 0.5f;
    const float angle = u5 * 3.14159274101257324f;
    const float sigma = 0.1f + 1.9f * u6;

    ImgParams p;
    p.ca = cosf(angle);
    p.sa = sinf(angle);
    const float syk = hc / (float)HH;
    const float sxk = wc / (float)WW;
    p.ay = syk;
    p.by = 0.5f * syk - 0.5f + fi;
    if (flip) {
        p.ax = -sxk;
        p.bx = ((float)WW - 0.5f) * sxk - 0.5f + fj;
    } else {
        p.ax = sxk;
        p.bx = 0.5f * sxk - 0.5f + fj;
    }
    float wk[5], wsum = 0.f;
    const float inv2s2 = 1.0f / (2.0f * sigma * sigma);
    #pragma unroll
    for (int k = 0; k < 5; ++k) {
        float d = (float)k - 2.0f;
        wk[k] = expf(-(d * d) * inv2s2);
        wsum += wk[k];
    }
    float inv = 1.0f / wsum;
    p.w0 = wk[0] * inv; p.w1 = wk[1] * inv; p.w2 = wk[2] * inv;
    p.w3 = wk[3] * inv; p.w4 = wk[4] * inv;
    p.pad = 0.f;
    params[n] = p;
}

__device__ __forceinline__ void swz_decode(int id, int swz, int& unit, int& tile) {
    if (swz) {
        int low  = id & 7;
        int rest = id >> 3;
        int uh   = rest / 49;
        tile     = rest - uh * 49;
        unit     = (uh << 3) | low;
    } else {
        unit = id / 49;
        tile = id - unit * 49;
    }
}

// ---------------- fused: augment section then copy section ----------------
__global__ __launch_bounds__(256) void fused_kernel(
        const float* __restrict__ M, const int* __restrict__ channel_idx,
        const int* __restrict__ copy_list, const ImgParams* __restrict__ params,
        const float* __restrict__ noise, float* __restrict__ out,
        int c, int n_aug, int n_copy, int aug_blocks, int swz) {
    const int tid = threadIdx.x;
    const int id  = blockIdx.x;

    if (id >= aug_blocks) {
        // -------- copy section: balanced across XCDs by construction --------
        int unit, tile;
        swz_decode(id - aug_blocks, swz, unit, tile);
        const int bi = unit / n_copy;
        const int ci = unit - bi * n_copy;
        const int ch = copy_list[ci];
        const size_t chanoff = ((size_t)bi * c + ch) * (HH * WW);
        const nt_float4* __restrict__ src = (const nt_float4*)(M + chanoff);
        nt_float4* __restrict__ dst = (nt_float4*)(out + chanoff);
        int off = tile * 256 + tid;
        __builtin_nontemporal_store(__builtin_nontemporal_load(&src[off]), &dst[off]);
        return;
    }

    // -------- augment section --------
    int unit, tile;
    swz_decode(id, swz, unit, tile);
    const int bi = unit / n_aug;
    const int a  = unit - bi * n_aug;
    const int ch = channel_idx[a];
    const int n  = unit;                    // bi * n_aug + a
    const size_t chanoff = ((size_t)bi * c + ch) * (HH * WW);

    const int ty = tile / TILES_X;
    const int tx = tile - ty * TILES_X;
    const int y0 = ty * TH;
    const int x0 = tx * TW;
    const bool refl = (ty == 0) || (ty == 6) || (tx == 0) || (tx == 6);  // block-uniform

    const ImgParams P = params[n];          // uniform -> scalar loads
    const float* __restrict__ img = M + chanoff;

    __shared__ __align__(16) float Box[BOXH * BOXW];   // 13.4 KB; aliased as Tmp later
    __shared__ __align__(16) float Wt[HALO][WTS];      // 5.1 KB

    const float cc = 111.5f;

    // ---- bounding box of source coords (block-uniform scalar math) ----
    const int ry_lo = max(y0 - 2, 0),  ry_hi = min(y0 + 33, HH - 1);
    const int rx_lo = max(x0 - 2, 0),  rx_hi = min(x0 + 33, WW - 1);
    const float dyl = (float)ry_lo - cc, dyh = (float)ry_hi - cc;
    const float dxl = (float)rx_lo - cc, dxh = (float)rx_hi - cc;
    float yr_min = cc + fminf(P.ca * dyl, P.ca * dyh) + P.sa * dxl;
    float yr_max = cc + fmaxf(P.ca * dyl, P.ca * dyh) + P.sa * dxh;
    float xr_min = cc + fminf(P.ca * dxl, P.ca * dxh) - P.sa * dyh;
    float xr_max = cc + fmaxf(P.ca * dxl, P.ca * dxh) - P.sa * dyl;
    // fully-in-bounds test on RAW bounds, conservative eps (0.01 >> fma ulp accum):
    // only SKIPS the per-sample check when its outcome is certain — never re-associated.
    const bool inball = (yr_min >= -0.49f) && (yr_max <= (float)HH - 0.51f) &&
                        (xr_min >= -0.49f) && (xr_max <= (float)WW - 0.51f);
    yr_min = fmaxf(yr_min, -0.5f); yr_max = fminf(yr_max, (float)HH - 0.5f);
    xr_min = fmaxf(xr_min, -0.5f); xr_max = fminf(xr_max, (float)WW - 0.5f);
    const float sy_min = P.ay * yr_min + P.by, sy_max = P.ay * yr_max + P.by;
    const float sx_a = P.ax * xr_min + P.bx,  sx_b = P.ax * xr_max + P.bx;
    const float sx_min = fminf(sx_a, sx_b), sx_max = fmaxf(sx_a, sx_b);
    // clamp-free test: per-sample sy/sx provably in [0, 223) (monotone affine;
    // association skew <= ~3e-5 << eps). Clamps become no-ops -> skip them.
    const bool clampfree = (sy_min >= 0.001f) && (sy_max <= 222.99f) &&
                           (sx_min >= 0.001f) && (sx_max <= 222.99f);
    const bool fastp = inball && clampfree;
    const int by0 = min(max((int)floorf(sy_min), 0), HH - 1);
    const int by1 = min(max((int)floorf(sy_max) + 1, 0), HH - 1);
    const int bx0 = min(max((int)floorf(sx_min), 0), WW - 1);
    const int bx1 = min(max((int)floorf(sx_max) + 1, 0), WW - 1);
    const int bh = max(by1 - by0 + 1, 0);   // <= 52 rows of real data (+1 pad row via clamp)

    // ---- float4 box staging: aligned columns, b128 LDS writes ----
    const int abx0  = bx0 & ~3;
    const int relw  = bx1 + 2 - abx0;                       // cols incl. +1 pad col
    const int ncols4 = min((relw + 3) >> 2, (WW - abx0) >> 2);
    {
        const int c4 = tid & 15;                            // 16 float4 columns
        if (c4 < ncols4) {
            const int scolb = abx0 + 4 * c4;
            for (int r = tid >> 4; r <= bh; r += 16) {
                int srow = min(by0 + r, HH - 1);
                nt_float4 v = *(const nt_float4*)(img + srow * WW + scolb);
                *(nt_float4*)&Box[r * BOXW + 4 * c4] = v;
            }
        }
    }
    // pad COLUMN (bx1==223): dup col 223, read from img directly -> no extra barrier
    if (bx1 == WW - 1) {                                    // block-uniform
        for (int r = tid; r <= bh; r += 256) {
            int srow = min(by0 + r, HH - 1);
            Box[r * BOXW + (WW - abx0)] = img[srow * WW + (WW - 1)];
        }
    }
    __syncthreads();

    // ---- warp into halo tile: thread = (row, 6 consecutive x) ----
    // NOTE: per-sample math uses the EXACT reference association
    // (yr = ca*dy + sa*dx + cc, explicit range check) — feeding the
    // discontinuous inb/zero-fill decision; do NOT re-associate (round-6 fail).
    // REFL/FAST are literals: interior tiles skip reflect; FAST tiles (inball &&
    // clampfree) skip the bounds check AND the index clamps (provable no-ops).
#define WARP_SAMPLES(REFL, FAST)                                               \
    {                                                                          \
        int ry;                                                                \
        if (REFL) { int ayv = abs(vy); ry = min(ayv, 2 * (HH - 1) - ayv); }    \
        else ry = vy;                                                          \
        const float dy = (float)ry - cc;                                       \
        _Pragma("unroll")                                                      \
        for (int j = 0; j < 6; ++j) {                                          \
            int vx = x0 + hx0 + j - 2;                                         \
            int rx;                                                            \
            if (REFL) { int axv = abs(vx); rx = min(axv, 2 * (WW - 1) - axv); }\
            else rx = vx;                                                      \
            float dx = (float)rx - cc;                                         \
            float yr = P.ca * dy + P.sa * dx + cc;                             \
            float xr = P.ca * dx - P.sa * dy + cc;                             \
            float val = 0.f;                                                   \
            if (FAST || (yr >= -0.5f && yr <= (float)HH - 0.5f &&              \
                         xr >= -0.5f && xr <= (float)WW - 0.5f)) {             \
                float sy = P.ay * yr + P.by;                                   \
                float sx = P.ax * xr + P.bx;                                   \
                float fy = floorf(sy), fx = floorf(sx);                        \
                float wy = sy - fy, wx = sx - fx;                              \
                int yi, xi;                                                    \
                if (FAST) { yi = (int)fy; xi = (int)fx; }   /* clamps no-op */ \
                else {                                                         \
                    yi = min(max((int)fy, 0), HH - 1);      /* clamp FIRST */  \
                    xi = min(max((int)fx, 0), WW - 1);                         \
                }                                                              \
                int k = yi * BOXW + xi + kbase;                                \
                float v00 = Box[k],        v01 = Box[k + 1];                   \
                float v10 = Box[k + BOXW], v11 = Box[k + BOXW + 1];            \
                float top = v00 + (v01 - v00) * wx;                            \
                float bot = v10 + (v11 - v10) * wx;                            \
                val = top + (bot - top) * wy;                                  \
            }                                                                  \
            acc[j] = val;                                                      \
        }                                                                      \
    }

    if (tid < 216) {
        const int hy  = tid / 6;
        const int g   = tid - hy * 6;
        const int hx0 = g * 6;
        const int vy  = y0 + hy - 2;
        const int kbase = -(by0 * BOXW + abx0);
        float acc[6];
        if (refl) {
            if (fastp) WARP_SAMPLES(1, 1) else WARP_SAMPLES(1, 0)
        } else {
            if (fastp) WARP_SAMPLES(0, 1) else WARP_SAMPLES(0, 0)
        }
        float2* wrow = (float2*)&Wt[hy][hx0];
        wrow[0] = make_float2(acc[0], acc[1]);
        wrow[1] = make_float2(acc[2], acc[3]);
        wrow[2] = make_float2(acc[4], acc[5]);
    }
#undef WARP_SAMPLES
    __syncthreads();

    // ---- vertical blur: 32 rows x 9 col-quads, float4 ----
    float* __restrict__ Tmp = Box;   // alias; safe after barrier
    for (int u2 = tid; u2 < TH * 9; u2 += 256) {
        int vy2 = u2 / 9, q = u2 - vy2 * 9;
        int x = 4 * q;
        float4 a0 = *(const float4*)&Wt[vy2][x];
        float4 a1 = *(const float4*)&Wt[vy2 + 1][x];
        float4 a2 = *(const float4*)&Wt[vy2 + 2][x];
        float4 a3 = *(const float4*)&Wt[vy2 + 3][x];
        float4 a4 = *(const float4*)&Wt[vy2 + 4][x];
        float4 s;
        s.x = P.w0 * a0.x + P.w1 * a1.x + P.w2 * a2.x + P.w3 * a3.x + P.w4 * a4.x;
        s.y = P.w0 * a0.y + P.w1 * a1.y + P.w2 * a2.y + P.w3 * a3.y + P.w4 * a4.y;
        s.z = P.w0 * a0.z + P.w1 * a1.z + P.w2 * a2.z + P.w3 * a3.z + P.w4 * a4.z;
        s.w = P.w0 * a0.w + P.w1 * a1.w + P.w2 * a2.w + P.w3 * a3.w + P.w4 * a4.w;
        *(float4*)&Tmp[vy2 * TMPS + x] = s;
    }
    __syncthreads();

    // ---- horizontal blur + noise + write, 4 px/thread, float4 ----
    const float* __restrict__ npz = noise + (size_t)n * (HH * WW);
    float* __restrict__ op = out + chanoff;
    {
        int yy = tid >> 3, p = tid & 7;
        int x = 4 * p;
        const float* t = Tmp + yy * TMPS + x;
        float4 ta = *(const float4*)(t);       // t0..t3
        float4 tb = *(const float4*)(t + 4);   // t4..t7
        float s0 = P.w0 * ta.x + P.w1 * ta.y + P.w2 * ta.z + P.w3 * ta.w + P.w4 * tb.x;
        float s1 = P.w0 * ta.y + P.w1 * ta.z + P.w2 * ta.w + P.w3 * tb.x + P.w4 * tb.y;
        float s2 = P.w0 * ta.z + P.w1 * ta.w + P.w2 * tb.x + P.w3 * tb.y + P.w4 * tb.z;
        float s3 = P.w0 * ta.w + P.w1 * tb.x + P.w2 * tb.y + P.w3 * tb.z + P.w4 * tb.w;
        size_t o = (size_t)(y0 + yy) * WW + (x0 + x);
        nt_float4 nz = __builtin_nontemporal_load((const nt_float4*)(npz + o));
        nt_float4 r;
        r.x = s0 + 0.05f * nz.x; r.y = s1 + 0.05f * nz.y;
        r.z = s2 + 0.05f * nz.z; r.w = s3 + 0.05f * nz.w;
        __builtin_nontemporal_store(r, (nt_float4*)(op + o));
    }
}

extern "C" void kernel_launch(void* const* d_in, const int* in_sizes, int n_in,
                              void* d_out, int out_size, void* d_ws, size_t ws_size,
                              hipStream_t stream) {
    const float* M           = (const float*)d_in[0];
    const int*   channel_idx = (const int*)d_in[1];
    const float* aug_u       = (const float*)d_in[2];
    const float* noise       = (const float*)d_in[3];
    float* out = (float*)d_out;

    const int n_aug = in_sizes[1];
    const int b     = in_sizes[2] / (n_aug * 7);
    const int c     = in_sizes[0] / (b * HH * WW);
    const int N     = b * n_aug;
    const int n_copy = c - n_aug;

    int* copy_list = (int*)d_ws;
    int* mark      = (int*)((char*)d_ws + 2048);
    ImgParams* params = (ImgParams*)((char*)d_ws + 8192);

    setup_kernel<<<1 + (N + 255) / 256, 256, 0, stream>>>(
        channel_idx, n_aug, c, copy_list, mark, aug_u, params, N);

    const int aug_units  = b * n_aug;
    const int copy_units = b * n_copy;
    const int aug_blocks = 49 * aug_units;
    const int copy_blocks = 49 * copy_units;
    const int swz = (aug_units % 8 == 0 && copy_units % 8 == 0) ? 1 : 0;
    fused_kernel<<<aug_blocks + copy_blocks, 256, 0, stream>>>(
        M, channel_idx, copy_list, params, noise, out,
        c, n_aug, n_copy, aug_blocks, swz);
}

// Round 20
// 175.170 us; speedup vs baseline: 1.6235x; 1.1677x over previous
//
#include <hip/hip_runtime.h>
#include <math.h>

#define HH 224
#define WW 224
#define TH 32
#define TW 32
#define TILES_X 7
#define HALO 36
#define BOXH 56
#define BOXW 60          // 240B rows: 16B-aligned for b128 LDS writes; granule advance 15 (mod 32)
#define WTS  36          // 144B rows: row advance = 1 bank-group (mod 8) -> ~2-way max (r16 win)
#define TMPS 36

typedef float nt_float4 __attribute__((ext_vector_type(4)));  // native vec for nontemporal builtins

struct __align__(16) ImgParams {
    float ca, sa, ay, by;   // rotation + y-affine (sy = ay*yr + by)
    float ax, bx, w0, w1;   // x-affine (flip folded in) + blur taps
    float w2, w3, w4, pad;
};

// ---------------- setup: copy_list (block 0) + per-image params (blocks 1..) ----------------
__global__ void setup_kernel(const int* __restrict__ channel_idx, int n_aug, int c,
                             int* __restrict__ copy_list, int* __restrict__ mark,
                             const float* __restrict__ aug_u,
                             ImgParams* __restrict__ params, int N) {
    if (blockIdx.x == 0) {
        int t = threadIdx.x;
        for (int i = t; i < c; i += 256) mark[i] = 0;
        __syncthreads();
        for (int i = t; i < n_aug; i += 256) mark[channel_idx[i]] = 1;
        __syncthreads();
        __shared__ int cnt;
        if (t == 0) cnt = 0;
        __syncthreads();
        for (int i = t; i < c; i += 256) {
            if (!mark[i]) {
                int p = atomicAdd(&cnt, 1);
                copy_list[p] = i;
            }
        }
        return;
    }
    int n = (blockIdx.x - 1) * blockDim.x + threadIdx.x;
    if (n >= N) return;
    const float* u = aug_u + (size_t)n * 7;
    const float u0 = u[0], u1 = u[1], u2 = u[2], u3 = u[3], u4 = u[4], u5 = u[5], u6 = u[6];

    const float area  = (float)(HH * WW) * (0.8f + 0.2f * u0);
    const float lo    = logf(0.75f);
    const float hi    = logf(4.0f / 3.0f);
    const float ratio = expf(lo + (hi - lo) * u1);
    float wc = sqrtf(area * ratio);
    float hc = sqrtf(area / ratio);
    wc = fminf(fmaxf(wc, 1.0f), (float)WW);
    hc = fminf(fmaxf(hc, 1.0f), (float)HH);
    const float fi    = u2 * ((float)HH - hc);
    const float fj    = u3 * ((float)WW - wc);
    const bool  flip  = u4 < 0.5f;
    const float angle = u5 * 3.14159274101257324f;
    const float sigma = 0.1f + 1.9f * u6;

    ImgParams p;
    p.ca = cosf(angle);
    p.sa = sinf(angle);
    const float syk = hc / (float)HH;
    const float sxk = wc / (float)WW;
    p.ay = syk;
    p.by = 0.5f * syk - 0.5f + fi;
    if (flip) {
        p.ax = -sxk;
        p.bx = ((float)WW - 0.5f) * sxk - 0.5f + fj;
    } else {
        p.ax = sxk;
        p.bx = 0.5f * sxk - 0.5f + fj;
    }
    float wk[5], wsum = 0.f;
    const float inv2s2 = 1.0f / (2.0f * sigma * sigma);
    #pragma unroll
    for (int k = 0; k < 5; ++k) {
        float d = (float)k - 2.0f;
        wk[k] = expf(-(d * d) * inv2s2);
        wsum += wk[k];
    }
    float inv = 1.0f / wsum;
    p.w0 = wk[0] * inv; p.w1 = wk[1] * inv; p.w2 = wk[2] * inv;
    p.w3 = wk[3] * inv; p.w4 = wk[4] * inv;
    p.pad = 0.f;
    params[n] = p;
}

__device__ __forceinline__ void swz_decode(int id, int swz, int& unit, int& tile) {
    if (swz) {
        int low  = id & 7;
        int rest = id >> 3;
        int uh   = rest / 49;
        tile     = rest - uh * 49;
        unit     = (uh << 3) | low;
    } else {
        unit = id / 49;
        tile = id - unit * 49;
    }
}

// ---------------- fused: aug blocks (each also copies one tile of a copy-channel) ----------------
// fuse=1 requires n_copy == n_aug: aug block (bi, a, tile) copies tile `tile` of
// channel copy_list[a] — exactly one float4/thread, issued at block start, stored at end.
// (r13/r14 lesson: copy in SEPARATE blocks churns LDS/occupancy; in-block costs nothing.)
__global__ __launch_bounds__(256) void fused_kernel(
        const float* __restrict__ M, const int* __restrict__ channel_idx,
        const int* __restrict__ copy_list, const ImgParams* __restrict__ params,
        const float* __restrict__ noise, float* __restrict__ out,
        int c, int n_aug, int n_copy, int aug_blocks, int swz, int fuse) {
    const int tid = threadIdx.x;
    const int id  = blockIdx.x;

    if (!fuse && id >= aug_blocks) {
        // -------- serial copy section (fallback when n_copy != n_aug) --------
        int unit, tile;
        swz_decode(id - aug_blocks, swz, unit, tile);
        const int bi = unit / n_copy;
        const int ci = unit - bi * n_copy;
        const int ch = copy_list[ci];
        const size_t chanoff = ((size_t)bi * c + ch) * (HH * WW);
        const nt_float4* __restrict__ src = (const nt_float4*)(M + chanoff);
        nt_float4* __restrict__ dst = (nt_float4*)(out + chanoff);
        int off = tile * 256 + tid;
        __builtin_nontemporal_store(__builtin_nontemporal_load(&src[off]), &dst[off]);
        return;
    }

    // -------- augment block --------
    int unit, tile;
    swz_decode(id, swz, unit, tile);
    const int bi = unit / n_aug;
    const int a  = unit - bi * n_aug;
    const int ch = channel_idx[a];
    const int n  = unit;                    // bi * n_aug + a
    const size_t chanoff = ((size_t)bi * c + ch) * (HH * WW);

    // ---- fused copy: issue load now (traffic spreads under aug VALU time) ----
    nt_float4 cpv;
    size_t coff = 0;
    if (fuse) {
        coff = ((size_t)bi * c + copy_list[a]) * (HH * WW) + (size_t)(tile * 256 + tid) * 4;
        cpv = __builtin_nontemporal_load((const nt_float4*)(M + coff));
    }

    const int ty = tile / TILES_X;
    const int tx = tile - ty * TILES_X;
    const int y0 = ty * TH;
    const int x0 = tx * TW;
    const bool refl = (ty == 0) || (ty == 6) || (tx == 0) || (tx == 6);  // block-uniform

    const ImgParams P = params[n];          // uniform -> scalar loads
    const float* __restrict__ img = M + chanoff;

    __shared__ __align__(16) float Box[BOXH * BOXW];   // 13.4 KB; aliased as Tmp later
    __shared__ __align__(16) float Wt[HALO][WTS];      // 5.1 KB

    const float cc = 111.5f;

    // ---- bounding box of source coords (block-uniform scalar math) ----
    const int ry_lo = max(y0 - 2, 0),  ry_hi = min(y0 + 33, HH - 1);
    const int rx_lo = max(x0 - 2, 0),  rx_hi = min(x0 + 33, WW - 1);
    const float dyl = (float)ry_lo - cc, dyh = (float)ry_hi - cc;
    const float dxl = (float)rx_lo - cc, dxh = (float)rx_hi - cc;
    float yr_min = cc + fminf(P.ca * dyl, P.ca * dyh) + P.sa * dxl;
    float yr_max = cc + fmaxf(P.ca * dyl, P.ca * dyh) + P.sa * dxh;
    float xr_min = cc + fminf(P.ca * dxl, P.ca * dxh) - P.sa * dyh;
    float xr_max = cc + fmaxf(P.ca * dxl, P.ca * dxh) - P.sa * dyl;
    // fully-in-bounds test on RAW bounds, conservative eps (0.01 >> fma ulp accum):
    // only SKIPS the per-sample check when its outcome is certain — never re-associated.
    const bool inball = (yr_min >= -0.49f) && (yr_max <= (float)HH - 0.51f) &&
                        (xr_min >= -0.49f) && (xr_max <= (float)WW - 0.51f);
    yr_min = fmaxf(yr_min, -0.5f); yr_max = fminf(yr_max, (float)HH - 0.5f);
    xr_min = fmaxf(xr_min, -0.5f); xr_max = fminf(xr_max, (float)WW - 0.5f);
    const float sy_min = P.ay * yr_min + P.by, sy_max = P.ay * yr_max + P.by;
    const float sx_a = P.ax * xr_min + P.bx,  sx_b = P.ax * xr_max + P.bx;
    const float sx_min = fminf(sx_a, sx_b), sx_max = fmaxf(sx_a, sx_b);
    // clamp-free test: per-sample sy/sx provably in [0, 223) (monotone affine;
    // association skew <= ~3e-5 << eps). Clamps become no-ops -> skip them.
    const bool clampfree = (sy_min >= 0.001f) && (sy_max <= 222.99f) &&
                           (sx_min >= 0.001f) && (sx_max <= 222.99f);
    const bool fastp = inball && clampfree;
    const int by0 = min(max((int)floorf(sy_min), 0), HH - 1);
    const int by1 = min(max((int)floorf(sy_max) + 1, 0), HH - 1);
    const int bx0 = min(max((int)floorf(sx_min), 0), WW - 1);
    const int bx1 = min(max((int)floorf(sx_max) + 1, 0), WW - 1);
    const int bh = max(by1 - by0 + 1, 0);   // <= 52 rows of real data (+1 pad row via clamp)

    // ---- float4 box staging: aligned columns, b128 LDS writes ----
    const int abx0  = bx0 & ~3;
    const int relw  = bx1 + 2 - abx0;                       // cols incl. +1 pad col
    const int ncols4 = min((relw + 3) >> 2, (WW - abx0) >> 2);
    {
        const int c4 = tid & 15;                            // 16 float4 columns
        if (c4 < ncols4) {
            const int scolb = abx0 + 4 * c4;
            for (int r = tid >> 4; r <= bh; r += 16) {
                int srow = min(by0 + r, HH - 1);
                nt_float4 v = *(const nt_float4*)(img + srow * WW + scolb);
                *(nt_float4*)&Box[r * BOXW + 4 * c4] = v;
            }
        }
    }
    // pad COLUMN (bx1==223): dup col 223, read from img directly -> no extra barrier
    if (bx1 == WW - 1) {                                    // block-uniform
        for (int r = tid; r <= bh; r += 256) {
            int srow = min(by0 + r, HH - 1);
            Box[r * BOXW + (WW - abx0)] = img[srow * WW + (WW - 1)];
        }
    }
    __syncthreads();

    // ---- warp into halo tile: thread = (row, 6 consecutive x) ----
    // NOTE: per-sample math uses the EXACT reference association
    // (yr = ca*dy + sa*dx + cc, explicit range check) — feeding the
    // discontinuous inb/zero-fill decision; do NOT re-associate (round-6 fail).
    // REFL/FAST are literals: interior tiles skip reflect; FAST tiles (inball &&
    // clampfree) skip the bounds check AND the index clamps (provable no-ops).
#define WARP_SAMPLES(REFL, FAST)                                               \
    {                                                                          \
        int ry;                                                                \
        if (REFL) { int ayv = abs(vy); ry = min(ayv, 2 * (HH - 1) - ayv); }    \
        else ry = vy;                                                          \
        const float dy = (float)ry - cc;                                       \
        _Pragma("unroll")                                                      \
        for (int j = 0; j < 6; ++j) {                                          \
            int vx = x0 + hx0 + j - 2;                                         \
            int rx;                                                            \
            if (REFL) { int axv = abs(vx); rx = min(axv, 2 * (WW - 1) - axv); }\
            else rx = vx;                                                      \
            float dx = (float)rx - cc;                                         \
            float yr = P.ca * dy + P.sa * dx + cc;                             \
            float xr = P.ca * dx - P.sa * dy + cc;                             \
            float val = 0.f;                                                   \
            if (FAST || (yr >= -0.5f && yr <= (float)HH - 0.5f &&              \
                         xr >= -0.5f && xr <= (float)WW - 0.5f)) {             \
                float sy = P.ay * yr + P.by;                                   \
                float sx = P.ax * xr + P.bx;                                   \
                float fy = floorf(sy), fx = floorf(sx);                        \
                float wy = sy - fy, wx = sx - fx;                              \
                int yi, xi;                                                    \
                if (FAST) { yi = (int)fy; xi = (int)fx; }   /* clamps no-op */ \
                else {                                                         \
                    yi = min(max((int)fy, 0), HH - 1);      /* clamp FIRST */  \
                    xi = min(max((int)fx, 0), WW - 1);                         \
                }                                                              \
                int k = yi * BOXW + xi + kbase;                                \
                float v00 = Box[k],        v01 = Box[k + 1];                   \
                float v10 = Box[k + BOXW], v11 = Box[k + BOXW + 1];            \
                float top = v00 + (v01 - v00) * wx;                            \
                float bot = v10 + (v11 - v10) * wx;                            \
                val = top + (bot - top) * wy;                                  \
            }                                                                  \
            acc[j] = val;                                                      \
        }                                                                      \
    }

    if (tid < 216) {
        const int hy  = tid / 6;
        const int g   = tid - hy * 6;
        const int hx0 = g * 6;
        const int vy  = y0 + hy - 2;
        const int kbase = -(by0 * BOXW + abx0);
        float acc[6];
        if (refl) {
            if (fastp) WARP_SAMPLES(1, 1) else WARP_SAMPLES(1, 0)
        } else {
            if (fastp) WARP_SAMPLES(0, 1) else WARP_SAMPLES(0, 0)
        }
        float2* wrow = (float2*)&Wt[hy][hx0];
        wrow[0] = make_float2(acc[0], acc[1]);
        wrow[1] = make_float2(acc[2], acc[3]);
        wrow[2] = make_float2(acc[4], acc[5]);
    }
#undef WARP_SAMPLES
    __syncthreads();

    // ---- vertical blur: 32 rows x 9 col-quads, float4 ----
    float* __restrict__ Tmp = Box;   // alias; safe after barrier
    for (int u2 = tid; u2 < TH * 9; u2 += 256) {
        int vy2 = u2 / 9, q = u2 - vy2 * 9;
        int x = 4 * q;
        float4 a0 = *(const float4*)&Wt[vy2][x];
        float4 a1 = *(const float4*)&Wt[vy2 + 1][x];
        float4 a2 = *(const float4*)&Wt[vy2 + 2][x];
        float4 a3 = *(const float4*)&Wt[vy2 + 3][x];
        float4 a4 = *(const float4*)&Wt[vy2 + 4][x];
        float4 s;
        s.x = P.w0 * a0.x + P.w1 * a1.x + P.w2 * a2.x + P.w3 * a3.x + P.w4 * a4.x;
        s.y = P.w0 * a0.y + P.w1 * a1.y + P.w2 * a2.y + P.w3 * a3.y + P.w4 * a4.y;
        s.z = P.w0 * a0.z + P.w1 * a1.z + P.w2 * a2.z + P.w3 * a3.z + P.w4 * a4.z;
        s.w = P.w0 * a0.w + P.w1 * a1.w + P.w2 * a2.w + P.w3 * a3.w + P.w4 * a4.w;
        *(float4*)&Tmp[vy2 * TMPS + x] = s;
    }
    __syncthreads();

    // ---- horizontal blur + noise + write, 4 px/thread, float4 ----
    const float* __restrict__ npz = noise + (size_t)n * (HH * WW);
    float* __restrict__ op = out + chanoff;
    {
        int yy = tid >> 3, p = tid & 7;
        int x = 4 * p;
        const float* t = Tmp + yy * TMPS + x;
        float4 ta = *(const float4*)(t);       // t0..t3
        float4 tb = *(const float4*)(t + 4);   // t4..t7
        float s0 = P.w0 * ta.x + P.w1 * ta.y + P.w2 * ta.z + P.w3 * ta.w + P.w4 * tb.x;
        float s1 = P.w0 * ta.y + P.w1 * ta.z + P.w2 * ta.w + P.w3 * tb.x + P.w4 * tb.y;
        float s2 = P.w0 * ta.z + P.w1 * ta.w + P.w2 * tb.x + P.w3 * tb.y + P.w4 * tb.z;
        float s3 = P.w0 * ta.w + P.w1 * tb.x + P.w2 * tb.y + P.w3 * tb.z + P.w4 * tb.w;
        size_t o = (size_t)(y0 + yy) * WW + (x0 + x);
        nt_float4 nz = __builtin_nontemporal_load((const nt_float4*)(npz + o));
        nt_float4 r;
        r.x = s0 + 0.05f * nz.x; r.y = s1 + 0.05f * nz.y;
        r.z = s2 + 0.05f * nz.z; r.w = s3 + 0.05f * nz.w;
        __builtin_nontemporal_store(r, (nt_float4*)(op + o));
    }

    // ---- fused copy: store (load issued at block start, long since landed) ----
    if (fuse) {
        __builtin_nontemporal_store(cpv, (nt_float4*)(out + coff));
    }
}

extern "C" void kernel_launch(void* const* d_in, const int* in_sizes, int n_in,
                              void* d_out, int out_size, void* d_ws, size_t ws_size,
                              hipStream_t stream) {
    const float* M           = (const float*)d_in[0];
    const int*   channel_idx = (const int*)d_in[1];
    const float* aug_u       = (const float*)d_in[2];
    const float* noise       = (const float*)d_in[3];
    float* out = (float*)d_out;

    const int n_aug = in_sizes[1];
    const int b     = in_sizes[2] / (n_aug * 7);
    const int c     = in_sizes[0] / (b * HH * WW);
    const int N     = b * n_aug;
    const int n_copy = c - n_aug;

    int* copy_list = (int*)d_ws;
    int* mark      = (int*)((char*)d_ws + 2048);
    ImgParams* params = (ImgParams*)((char*)d_ws + 8192);

    setup_kernel<<<1 + (N + 255) / 256, 256, 0, stream>>>(
        channel_idx, n_aug, c, copy_list, mark, aug_u, params, N);

    const int aug_units  = b * n_aug;
    const int copy_units = b * n_copy;
    const int aug_blocks = 49 * aug_units;
    const int copy_blocks = 49 * copy_units;
    const int swz  = (aug_units % 8 == 0 && copy_units % 8 == 0) ? 1 : 0;
    const int fuse = (n_copy == n_aug) ? 1 : 0;   // 1:1 block mapping
    const int grid = fuse ? aug_blocks : (aug_blocks + copy_blocks);
    fused_kernel<<<grid, 256, 0, stream>>>(
        M, channel_idx, copy_list, params, noise, out,
        c, n_aug, n_copy, aug_blocks, swz, fuse);
}